// Round 1
// baseline (2540.859 us; speedup 1.0000x reference)
//
#include <hip/hip_runtime.h>

#define N_NODES 50000
#define N_EDGES 800000
#define F 128
#define HDIM 64
#define NE 3
#define NGRAPH 64
#define NC 3
#define BN_EPS 1e-5f

// ---------------- degree ----------------
__global__ void k_deg_acc(const int* __restrict__ dst, float* __restrict__ acc) {
    int e = blockIdx.x * 256 + threadIdx.x;
    if (e < N_EDGES) atomicAdd(&acc[dst[e]], 1.0f);
}

__global__ void k_deg_fin(float* __restrict__ deg_isqrt, float* __restrict__ deg_inv) {
    int n = blockIdx.x * 256 + threadIdx.x;
    if (n < N_NODES) {
        float d = deg_inv[n] + 1.0f;   // deg_inv currently holds the in-degree count
        deg_isqrt[n] = rsqrtf(d);
        deg_inv[n] = 1.0f / d;
    }
}

// ---------------- gating MLP: softmax(relu(x@W1+b1)@W2+b2) ----------------
__global__ __launch_bounds__(256) void k_gate(const float* __restrict__ x,
        const float* __restrict__ W1, const float* __restrict__ b1,
        const float* __restrict__ W2, const float* __restrict__ b2,
        float* __restrict__ gate) {
    __shared__ float hs[8][32];
    int tid = threadIdx.x;
    int grp = tid >> 5, j = tid & 31;
    int n = blockIdx.x * 8 + grp;
    float acc = b1[j];
    if (n < N_NODES) {
        const float* xr = x + (size_t)n * F;
        #pragma unroll 8
        for (int k = 0; k < F; ++k) acc = fmaf(xr[k], W1[k * 32 + j], acc);
    }
    hs[grp][j] = fmaxf(acc, 0.f);
    __syncthreads();
    if (tid < 8) {
        int nn = blockIdx.x * 8 + tid;
        if (nn < N_NODES) {
            float l0 = b2[0], l1 = b2[1], l2 = b2[2];
            #pragma unroll
            for (int k = 0; k < 32; ++k) {
                float h = hs[tid][k];
                l0 = fmaf(h, W2[k * 3 + 0], l0);
                l1 = fmaf(h, W2[k * 3 + 1], l1);
                l2 = fmaf(h, W2[k * 3 + 2], l2);
            }
            float m = fmaxf(l0, fmaxf(l1, l2));
            float e0 = __expf(l0 - m), e1 = __expf(l1 - m), e2 = __expf(l2 - m);
            float inv = 1.f / (e0 + e1 + e2);
            gate[nn * 3 + 0] = e0 * inv;
            gate[nn * 3 + 1] = e1 * inv;
            gate[nn * 3 + 2] = e2 * inv;
        }
    }
}

// ---------------- GCN prop: self-loop term (initializes output) ----------------
template<int F4>
__global__ void k_self(const float* __restrict__ hin, const float* __restrict__ deg_inv,
                       float* __restrict__ out) {
    int idx = blockIdx.x * 256 + threadIdx.x;
    int n = idx / F4, c = idx % F4;
    if (n >= N_NODES) return;
    float4 v = ((const float4*)hin)[(size_t)n * F4 + c];
    float s = deg_inv[n];
    float4 o = make_float4(v.x * s, v.y * s, v.z * s, v.w * s);
    ((float4*)out)[(size_t)n * F4 + c] = o;
}

// ---------------- GCN prop: edge scatter with atomics ----------------
template<int F4>
__global__ void k_scatter(const int* __restrict__ ei, const float* __restrict__ isq,
                          const float* __restrict__ hin, float* __restrict__ out) {
    int t = blockIdx.x * 256 + threadIdx.x;
    int e = t / F4, c = t % F4;
    if (e >= N_EDGES) return;
    int s = ei[e], d = ei[N_EDGES + e];
    float norm = isq[s] * isq[d];
    float4 v = ((const float4*)hin)[(size_t)s * F4 + c];
    float* ob = out + (size_t)d * (F4 * 4) + c * 4;
    atomicAdd(ob + 0, norm * v.x);
    atomicAdd(ob + 1, norm * v.y);
    atomicAdd(ob + 2, norm * v.z);
    atomicAdd(ob + 3, norm * v.w);
}

// ---------------- experts + gated combine: h1pre[n][h] = sum_e g[n,e]*(xp[n]@Wexp[e]+bexp[e]) ----------------
__global__ __launch_bounds__(256) void k_expert(const float* __restrict__ xp,
        const float* __restrict__ Wexp, const float* __restrict__ bexp,
        const float* __restrict__ gate, float* __restrict__ h1pre) {
    __shared__ float4 xs[64 * 32];   // [node][k4]  32 KB
    __shared__ float  wsd[128 * 64]; // [k][h]      32 KB
    int tid = threadIdx.x;
    int nbase = blockIdx.x * 64;
    for (int i = tid; i < 64 * 32; i += 256) {
        int r = i >> 5, c = i & 31;
        int n = nbase + r; if (n >= N_NODES) n = N_NODES - 1;
        xs[i] = ((const float4*)xp)[(size_t)n * 32 + c];
    }
    int h = tid & 63;
    int iq = tid >> 6;
    int n0 = nbase + iq * 16;
    float comb[16];
    #pragma unroll
    for (int i = 0; i < 16; ++i) comb[i] = 0.f;
    for (int e = 0; e < NE; ++e) {
        __syncthreads();
        const float4* wsrc = (const float4*)(Wexp + (size_t)e * F * HDIM);
        for (int i = tid; i < 128 * 16; i += 256) ((float4*)wsd)[i] = wsrc[i];
        __syncthreads();
        float be = bexp[e * HDIM + h];
        float acc[16];
        #pragma unroll
        for (int i = 0; i < 16; ++i) acc[i] = 0.f;
        for (int k4 = 0; k4 < 32; ++k4) {
            float w0 = wsd[(k4 * 4 + 0) * 64 + h];
            float w1 = wsd[(k4 * 4 + 1) * 64 + h];
            float w2 = wsd[(k4 * 4 + 2) * 64 + h];
            float w3 = wsd[(k4 * 4 + 3) * 64 + h];
            #pragma unroll
            for (int i = 0; i < 16; ++i) {
                float4 xv = xs[(iq * 16 + i) * 32 + k4];
                acc[i] = fmaf(xv.x, w0, acc[i]);
                acc[i] = fmaf(xv.y, w1, acc[i]);
                acc[i] = fmaf(xv.z, w2, acc[i]);
                acc[i] = fmaf(xv.w, w3, acc[i]);
            }
        }
        #pragma unroll
        for (int i = 0; i < 16; ++i) {
            int n = n0 + i;
            float gg = (n < N_NODES) ? gate[n * 3 + e] : 0.f;
            comb[i] = fmaf(gg, acc[i] + be, comb[i]);
        }
    }
    #pragma unroll
    for (int i = 0; i < 16; ++i) {
        int n = n0 + i;
        if (n < N_NODES) h1pre[(size_t)n * HDIM + h] = comb[i];
    }
}

// ---------------- column sums / sumsq for batchnorm ----------------
__global__ __launch_bounds__(256) void k_stats(const float* __restrict__ hm, float* __restrict__ sums) {
    int tid = threadIdx.x;
    int c = tid & 63, q = tid >> 6;
    float s = 0.f, s2 = 0.f;
    for (int r = blockIdx.x * 4 + q; r < N_NODES; r += gridDim.x * 4) {
        float v = hm[(size_t)r * 64 + c];
        s += v; s2 = fmaf(v, v, s2);
    }
    __shared__ float red[2][4][64];
    red[0][q][c] = s; red[1][q][c] = s2;
    __syncthreads();
    if (q == 0) {
        s  = red[0][0][c] + red[0][1][c] + red[0][2][c] + red[0][3][c];
        s2 = red[1][0][c] + red[1][1][c] + red[1][2][c] + red[1][3][c];
        atomicAdd(&sums[c], s);
        atomicAdd(&sums[64 + c], s2);
    }
}

__global__ void k_statfin(const float* __restrict__ sums, const float* __restrict__ g,
                          const float* __restrict__ b, float* __restrict__ scsh) {
    int c = threadIdx.x;  // 64 threads
    float mu = sums[c] * (1.0f / N_NODES);
    float var = sums[64 + c] * (1.0f / N_NODES) - mu * mu;
    float rs = rsqrtf(var + BN_EPS);
    float sc = rs * g[c];
    scsh[c] = sc;
    scsh[64 + c] = b[c] - mu * sc;
}

// ---------------- bn1 + relu fused into h1 @ W2 ----------------
__global__ __launch_bounds__(256) void k_w2(const float* __restrict__ h1pre,
        const float* __restrict__ scsh, const float* __restrict__ W2, float* __restrict__ y) {
    __shared__ float4 hsd[64 * 16];  // 16 KB
    __shared__ float  wsd[64 * 64];  // 16 KB
    int tid = threadIdx.x;
    int nbase = blockIdx.x * 64;
    for (int i = tid; i < 64 * 16; i += 256) ((float4*)wsd)[i] = ((const float4*)W2)[i];
    for (int i = tid; i < 64 * 16; i += 256) {
        int r = i >> 4, c = i & 15;
        int n = nbase + r; if (n >= N_NODES) n = N_NODES - 1;
        float4 v  = ((const float4*)h1pre)[(size_t)n * 16 + c];
        float4 sc = ((const float4*)scsh)[c];
        float4 sh = ((const float4*)scsh)[16 + c];
        v.x = fmaxf(fmaf(v.x, sc.x, sh.x), 0.f);
        v.y = fmaxf(fmaf(v.y, sc.y, sh.y), 0.f);
        v.z = fmaxf(fmaf(v.z, sc.z, sh.z), 0.f);
        v.w = fmaxf(fmaf(v.w, sc.w, sh.w), 0.f);
        hsd[i] = v;
    }
    __syncthreads();
    int h = tid & 63, iq = tid >> 6;
    float acc[16];
    #pragma unroll
    for (int i = 0; i < 16; ++i) acc[i] = 0.f;
    for (int k4 = 0; k4 < 16; ++k4) {
        float w0 = wsd[(k4 * 4 + 0) * 64 + h];
        float w1 = wsd[(k4 * 4 + 1) * 64 + h];
        float w2v = wsd[(k4 * 4 + 2) * 64 + h];
        float w3 = wsd[(k4 * 4 + 3) * 64 + h];
        #pragma unroll
        for (int i = 0; i < 16; ++i) {
            float4 xv = hsd[(iq * 16 + i) * 16 + k4];
            acc[i] = fmaf(xv.x, w0, acc[i]);
            acc[i] = fmaf(xv.y, w1, acc[i]);
            acc[i] = fmaf(xv.z, w2v, acc[i]);
            acc[i] = fmaf(xv.w, w3, acc[i]);
        }
    }
    #pragma unroll
    for (int i = 0; i < 16; ++i) {
        int n = nbase + iq * 16 + i;
        if (n < N_NODES) y[(size_t)n * 64 + h] = acc[i];
    }
}

// ---------------- per-graph node count ----------------
__global__ void k_cnt(const int* __restrict__ batch, float* __restrict__ cnt) {
    int n = blockIdx.x * 256 + threadIdx.x;
    if (n < N_NODES) atomicAdd(&cnt[batch[n]], 1.0f);
}

// ---------------- bn2 + relu + pooling (sum & max), run-length batched atomics ----------------
__global__ __launch_bounds__(256) void k_pool(const float* __restrict__ xp2,
        const float* __restrict__ scsh2, const int* __restrict__ batch,
        float* __restrict__ psum, unsigned int* __restrict__ pmax) {
    int tid = threadIdx.x;
    int h = tid & 63, q = tid >> 6;
    float sc = scsh2[h], sh = scsh2[64 + h];
    int base = blockIdx.x * 256;
    int curg = -1; float ls = 0.f, lm = 0.f;
    for (int j = 0; j < 64; ++j) {
        int r = base + j * 4 + q;
        if (r >= N_NODES) break;
        int g = batch[r];
        if (g != curg) {
            if (curg >= 0) {
                atomicAdd(&psum[curg * 64 + h], ls);
                atomicMax(&pmax[curg * 64 + h], __float_as_uint(lm));
            }
            curg = g; ls = 0.f; lm = 0.f;
        }
        float v = fmaxf(fmaf(xp2[(size_t)r * 64 + h], sc, sh), 0.f);
        ls += v; lm = fmaxf(lm, v);
    }
    if (curg >= 0) {
        atomicAdd(&psum[curg * 64 + h], ls);
        atomicMax(&pmax[curg * 64 + h], __float_as_uint(lm));
    }
}

// ---------------- classifier: [mean|max|sum] @ cls_W + cls_b ----------------
__global__ void k_cls(const float* __restrict__ psum, const unsigned int* __restrict__ pmax,
                      const float* __restrict__ cnt, const float* __restrict__ Wc,
                      const float* __restrict__ bc, float* __restrict__ out) {
    int t = threadIdx.x;
    if (t >= NGRAPH * NC) return;
    int g = t / NC, c = t % NC;
    float invc = 1.f / fmaxf(cnt[g], 1.f);
    float acc = bc[c];
    #pragma unroll 8
    for (int j = 0; j < 64; ++j) {
        float s = psum[g * 64 + j];
        float mx = __uint_as_float(pmax[g * 64 + j]);
        acc = fmaf(s * invc, Wc[j * 3 + c], acc);
        acc = fmaf(mx, Wc[(64 + j) * 3 + c], acc);
        acc = fmaf(s, Wc[(128 + j) * 3 + c], acc);
    }
    out[g * NC + c] = acc;
}

extern "C" void kernel_launch(void* const* d_in, const int* in_sizes, int n_in,
                              void* d_out, int out_size, void* d_ws, size_t ws_size,
                              hipStream_t stream) {
    const float* x    = (const float*)d_in[0];
    const int*   ei   = (const int*)d_in[1];
    const int*   batch= (const int*)d_in[2];
    const float* Wexp = (const float*)d_in[3];
    const float* bexp = (const float*)d_in[4];
    const float* gW1  = (const float*)d_in[5];
    const float* gb1  = (const float*)d_in[6];
    const float* gW2  = (const float*)d_in[7];
    const float* gb2  = (const float*)d_in[8];
    const float* W2   = (const float*)d_in[9];
    // d_in[10] = b2: provably cancels inside bn2 (per-column constant shift)
    const float* bn1g = (const float*)d_in[11];
    const float* bn1b = (const float*)d_in[12];
    const float* bn2g = (const float*)d_in[13];
    const float* bn2b = (const float*)d_in[14];
    const float* clsW = (const float*)d_in[15];
    const float* clsb = (const float*)d_in[16];
    float* out = (float*)d_out;

    float* ws = (float*)d_ws;
    const size_t NN = N_NODES;
    float* deg_isqrt = ws;
    float* deg_inv   = ws + NN;          // doubles as degree accumulator
    float* gate      = ws + 2 * NN;      // N*3
    float* h1pre     = ws + 5 * NN;      // N*64
    float* xp        = ws + 69 * NN;     // N*128 (reused below)
    float* y         = xp;               // N*64   (after k_expert, xp is dead)
    float* xp2       = xp + 64 * NN;     // N*64
    float* stats     = ws + 197 * NN;
    float* sums1 = stats,        *scsh1 = stats + 128;
    float* sums2 = stats + 256,  *scsh2 = stats + 384;
    float* psum  = stats + 512;                       // G*64
    unsigned int* pmax = (unsigned int*)(stats + 512 + 4096); // G*64
    float* cnt   = stats + 512 + 8192;                // G

    hipMemsetAsync(deg_inv, 0, NN * sizeof(float), stream);
    hipMemsetAsync(stats, 0, (512 + 8192 + 64) * sizeof(float), stream);

    k_deg_acc<<<(N_EDGES + 255) / 256, 256, 0, stream>>>(ei + N_EDGES, deg_inv);
    k_deg_fin<<<(N_NODES + 255) / 256, 256, 0, stream>>>(deg_isqrt, deg_inv);
    k_gate<<<(N_NODES + 7) / 8, 256, 0, stream>>>(x, gW1, gb1, gW2, gb2, gate);
    k_self<32><<<(N_NODES * 32 + 255) / 256, 256, 0, stream>>>(x, deg_inv, xp);
    k_scatter<32><<<(N_EDGES * 32) / 256, 256, 0, stream>>>(ei, deg_isqrt, x, xp);
    k_expert<<<(N_NODES + 63) / 64, 256, 0, stream>>>(xp, Wexp, bexp, gate, h1pre);
    k_stats<<<128, 256, 0, stream>>>(h1pre, sums1);
    k_statfin<<<1, 64, 0, stream>>>(sums1, bn1g, bn1b, scsh1);
    k_w2<<<(N_NODES + 63) / 64, 256, 0, stream>>>(h1pre, scsh1, W2, y);
    k_self<16><<<(N_NODES * 16 + 255) / 256, 256, 0, stream>>>(y, deg_inv, xp2);
    k_scatter<16><<<(N_EDGES * 16) / 256, 256, 0, stream>>>(ei, deg_isqrt, y, xp2);
    k_stats<<<128, 256, 0, stream>>>(xp2, sums2);
    k_statfin<<<1, 64, 0, stream>>>(sums2, bn2g, bn2b, scsh2);
    k_cnt<<<(N_NODES + 255) / 256, 256, 0, stream>>>(batch, cnt);
    k_pool<<<(N_NODES + 255) / 256, 256, 0, stream>>>(xp2, scsh2, batch, psum, pmax);
    k_cls<<<1, 256, 0, stream>>>(psum, pmax, cnt, clsW, clsb, out);
}

// Round 2
// 794.700 us; speedup vs baseline: 3.1973x; 3.1973x over previous
//
#include <hip/hip_runtime.h>

#define N_NODES 50000
#define N_EDGES 800000
#define F 128
#define HDIM 64
#define NE 3
#define NGRAPH 64
#define NC 3
#define BN_EPS 1e-5f

// ---------------- degree count (int atomics) ----------------
__global__ void k_degi(const int* __restrict__ dst, int* __restrict__ ideg) {
    int e = blockIdx.x * 256 + threadIdx.x;
    if (e < N_EDGES) atomicAdd(&ideg[dst[e]], 1);
}

__global__ void k_deg_fin(const int* __restrict__ ideg, float* __restrict__ deg_isqrt,
                          float* __restrict__ deg_inv) {
    int n = blockIdx.x * 256 + threadIdx.x;
    if (n < N_NODES) {
        float d = (float)ideg[n] + 1.0f;
        deg_isqrt[n] = rsqrtf(d);
        deg_inv[n] = 1.0f / d;
    }
}

// ---------------- exclusive scan of degrees -> row_start (single block) ----------------
__global__ __launch_bounds__(1024) void k_scan(const int* __restrict__ ideg,
                                               int* __restrict__ row_start) {
    __shared__ int wsums[16];
    __shared__ int s_carry;
    int tid = threadIdx.x;
    int lane = tid & 63, wid = tid >> 6;
    if (tid == 0) s_carry = 0;
    __syncthreads();
    for (int base = 0; base < N_NODES; base += 1024) {
        int i = base + tid;
        int v = (i < N_NODES) ? ideg[i] : 0;
        int x = v;
        #pragma unroll
        for (int off = 1; off < 64; off <<= 1) {
            int u = __shfl_up(x, off, 64);
            if (lane >= off) x += u;
        }
        if (lane == 63) wsums[wid] = x;
        __syncthreads();
        if (wid == 0) {
            int wv = (lane < 16) ? wsums[lane] : 0;
            #pragma unroll
            for (int off = 1; off < 16; off <<= 1) {
                int u = __shfl_up(wv, off, 64);
                if (lane >= off) wv += u;
            }
            if (lane < 16) wsums[lane] = wv;
        }
        __syncthreads();
        int carry = s_carry;
        int excl = carry + (wid > 0 ? wsums[wid - 1] : 0) + (x - v);
        if (i < N_NODES) row_start[i] = excl;
        __syncthreads();
        if (tid == 1023) s_carry = carry + wsums[15];
        __syncthreads();
    }
    if (tid == 0) row_start[N_NODES] = s_carry;
}

// ---------------- fill CSR (src only; slot via atomic cursor) ----------------
__global__ void k_fill(const int* __restrict__ ei, const int* __restrict__ row_start,
                       int* __restrict__ cursor, int* __restrict__ csr_src) {
    int e = blockIdx.x * 256 + threadIdx.x;
    if (e >= N_EDGES) return;
    int s = ei[e], d = ei[N_EDGES + e];
    int slot = atomicAdd(&cursor[d], 1);
    csr_src[row_start[d] + slot] = s;
}

// ---------------- gating MLP: softmax(relu(x@W1+b1)@W2+b2) ----------------
__global__ __launch_bounds__(256) void k_gate(const float* __restrict__ x,
        const float* __restrict__ W1, const float* __restrict__ b1,
        const float* __restrict__ W2, const float* __restrict__ b2,
        float* __restrict__ gate) {
    __shared__ float hs[8][32];
    int tid = threadIdx.x;
    int grp = tid >> 5, j = tid & 31;
    int n = blockIdx.x * 8 + grp;
    float acc = b1[j];
    if (n < N_NODES) {
        const float* xr = x + (size_t)n * F;
        #pragma unroll 8
        for (int k = 0; k < F; ++k) acc = fmaf(xr[k], W1[k * 32 + j], acc);
    }
    hs[grp][j] = fmaxf(acc, 0.f);
    __syncthreads();
    if (tid < 8) {
        int nn = blockIdx.x * 8 + tid;
        if (nn < N_NODES) {
            float l0 = b2[0], l1 = b2[1], l2 = b2[2];
            #pragma unroll
            for (int k = 0; k < 32; ++k) {
                float h = hs[tid][k];
                l0 = fmaf(h, W2[k * 3 + 0], l0);
                l1 = fmaf(h, W2[k * 3 + 1], l1);
                l2 = fmaf(h, W2[k * 3 + 2], l2);
            }
            float m = fmaxf(l0, fmaxf(l1, l2));
            float e0 = __expf(l0 - m), e1 = __expf(l1 - m), e2 = __expf(l2 - m);
            float inv = 1.f / (e0 + e1 + e2);
            gate[nn * 3 + 0] = e0 * inv;
            gate[nn * 3 + 1] = e1 * inv;
            gate[nn * 3 + 2] = e2 * inv;
        }
    }
}

// ---------------- GCN prop via CSR gather (self-loop folded in) ----------------
template<int F4>   // row width in float4: 32 (F=128) or 16 (H=64)
__global__ __launch_bounds__(256) void k_gather(const int* __restrict__ csr_src,
        const int* __restrict__ row_start, const float* __restrict__ deg_isqrt,
        const float* __restrict__ deg_inv, const float* __restrict__ hin,
        float* __restrict__ out) {
    constexpr int GPB = 256 / F4;
    int lane = threadIdx.x % F4;
    int grp  = threadIdx.x / F4;
    int n = blockIdx.x * GPB + grp;
    if (n >= N_NODES) return;
    const float4* hin4 = (const float4*)hin;
    int beg = row_start[n], end = row_start[n + 1];
    float isq_n = deg_isqrt[n];
    float di = deg_inv[n];
    float4 sv = hin4[(size_t)n * F4 + lane];
    float ax = sv.x * di, ay = sv.y * di, az = sv.z * di, aw = sv.w * di;
    int j = beg;
    for (; j + 1 < end; j += 2) {
        int s0 = csr_src[j], s1 = csr_src[j + 1];
        float m0 = isq_n * deg_isqrt[s0];
        float m1 = isq_n * deg_isqrt[s1];
        float4 v0 = hin4[(size_t)s0 * F4 + lane];
        float4 v1 = hin4[(size_t)s1 * F4 + lane];
        ax = fmaf(m0, v0.x, ax); ay = fmaf(m0, v0.y, ay);
        az = fmaf(m0, v0.z, az); aw = fmaf(m0, v0.w, aw);
        ax = fmaf(m1, v1.x, ax); ay = fmaf(m1, v1.y, ay);
        az = fmaf(m1, v1.z, az); aw = fmaf(m1, v1.w, aw);
    }
    if (j < end) {
        int s0 = csr_src[j];
        float m0 = isq_n * deg_isqrt[s0];
        float4 v0 = hin4[(size_t)s0 * F4 + lane];
        ax = fmaf(m0, v0.x, ax); ay = fmaf(m0, v0.y, ay);
        az = fmaf(m0, v0.z, az); aw = fmaf(m0, v0.w, aw);
    }
    ((float4*)out)[(size_t)n * F4 + lane] = make_float4(ax, ay, az, aw);
}

// ---------------- experts + gated combine (W in LDS, x direct from global) ----------------
__global__ __launch_bounds__(256) void k_expert(const float* __restrict__ xp,
        const float* __restrict__ Wexp, const float* __restrict__ bexp,
        const float* __restrict__ gate, float* __restrict__ h1pre) {
    __shared__ float wsd[128 * 64];   // 32 KB, one expert at a time
    int tid = threadIdx.x;
    int h = tid & 63, iq = tid >> 6;
    int n0 = blockIdx.x * 32 + iq * 8;
    const float4* xr[8];
    #pragma unroll
    for (int i = 0; i < 8; ++i) {
        int n = n0 + i; if (n >= N_NODES) n = N_NODES - 1;
        xr[i] = (const float4*)xp + (size_t)n * 32;
    }
    float comb[8];
    #pragma unroll
    for (int i = 0; i < 8; ++i) comb[i] = 0.f;
    for (int e = 0; e < NE; ++e) {
        __syncthreads();
        const float4* wsrc = (const float4*)(Wexp + (size_t)e * F * HDIM);
        for (int i = tid; i < 128 * 16; i += 256) ((float4*)wsd)[i] = wsrc[i];
        __syncthreads();
        float be = bexp[e * HDIM + h];
        float acc[8];
        #pragma unroll
        for (int i = 0; i < 8; ++i) acc[i] = 0.f;
        for (int k4 = 0; k4 < 32; ++k4) {
            float w0 = wsd[(k4 * 4 + 0) * 64 + h];
            float w1 = wsd[(k4 * 4 + 1) * 64 + h];
            float w2 = wsd[(k4 * 4 + 2) * 64 + h];
            float w3 = wsd[(k4 * 4 + 3) * 64 + h];
            #pragma unroll
            for (int i = 0; i < 8; ++i) {
                float4 xv = xr[i][k4];
                acc[i] = fmaf(xv.x, w0, acc[i]);
                acc[i] = fmaf(xv.y, w1, acc[i]);
                acc[i] = fmaf(xv.z, w2, acc[i]);
                acc[i] = fmaf(xv.w, w3, acc[i]);
            }
        }
        #pragma unroll
        for (int i = 0; i < 8; ++i) {
            int n = n0 + i;
            float gg = (n < N_NODES) ? gate[n * 3 + e] : 0.f;
            comb[i] = fmaf(gg, acc[i] + be, comb[i]);
        }
    }
    #pragma unroll
    for (int i = 0; i < 8; ++i) {
        int n = n0 + i;
        if (n < N_NODES) h1pre[(size_t)n * HDIM + h] = comb[i];
    }
}

// ---------------- column sums / sumsq for batchnorm ----------------
__global__ __launch_bounds__(256) void k_stats(const float* __restrict__ hm, float* __restrict__ sums) {
    int tid = threadIdx.x;
    int c = tid & 63, q = tid >> 6;
    float s = 0.f, s2 = 0.f;
    for (int r = blockIdx.x * 4 + q; r < N_NODES; r += gridDim.x * 4) {
        float v = hm[(size_t)r * 64 + c];
        s += v; s2 = fmaf(v, v, s2);
    }
    __shared__ float red[2][4][64];
    red[0][q][c] = s; red[1][q][c] = s2;
    __syncthreads();
    if (q == 0) {
        s  = red[0][0][c] + red[0][1][c] + red[0][2][c] + red[0][3][c];
        s2 = red[1][0][c] + red[1][1][c] + red[1][2][c] + red[1][3][c];
        atomicAdd(&sums[c], s);
        atomicAdd(&sums[64 + c], s2);
    }
}

__global__ void k_statfin(const float* __restrict__ sums, const float* __restrict__ g,
                          const float* __restrict__ b, float* __restrict__ scsh) {
    int c = threadIdx.x;  // 64 threads
    float mu = sums[c] * (1.0f / N_NODES);
    float var = sums[64 + c] * (1.0f / N_NODES) - mu * mu;
    float rs = rsqrtf(var + BN_EPS);
    float sc = rs * g[c];
    scsh[c] = sc;
    scsh[64 + c] = b[c] - mu * sc;
}

// ---------------- bn1 + relu fused into h1 @ W2 ----------------
__global__ __launch_bounds__(256) void k_w2(const float* __restrict__ h1pre,
        const float* __restrict__ scsh, const float* __restrict__ W2, float* __restrict__ y) {
    __shared__ float4 hsd[64 * 16];  // 16 KB
    __shared__ float  wsd[64 * 64];  // 16 KB
    int tid = threadIdx.x;
    int nbase = blockIdx.x * 64;
    for (int i = tid; i < 64 * 16; i += 256) ((float4*)wsd)[i] = ((const float4*)W2)[i];
    for (int i = tid; i < 64 * 16; i += 256) {
        int r = i >> 4, c = i & 15;
        int n = nbase + r; if (n >= N_NODES) n = N_NODES - 1;
        float4 v  = ((const float4*)h1pre)[(size_t)n * 16 + c];
        float4 sc = ((const float4*)scsh)[c];
        float4 sh = ((const float4*)scsh)[16 + c];
        v.x = fmaxf(fmaf(v.x, sc.x, sh.x), 0.f);
        v.y = fmaxf(fmaf(v.y, sc.y, sh.y), 0.f);
        v.z = fmaxf(fmaf(v.z, sc.z, sh.z), 0.f);
        v.w = fmaxf(fmaf(v.w, sc.w, sh.w), 0.f);
        hsd[i] = v;
    }
    __syncthreads();
    int h = tid & 63, iq = tid >> 6;
    float acc[16];
    #pragma unroll
    for (int i = 0; i < 16; ++i) acc[i] = 0.f;
    for (int k4 = 0; k4 < 16; ++k4) {
        float w0 = wsd[(k4 * 4 + 0) * 64 + h];
        float w1 = wsd[(k4 * 4 + 1) * 64 + h];
        float w2v = wsd[(k4 * 4 + 2) * 64 + h];
        float w3 = wsd[(k4 * 4 + 3) * 64 + h];
        #pragma unroll
        for (int i = 0; i < 16; ++i) {
            float4 xv = hsd[(iq * 16 + i) * 16 + k4];
            acc[i] = fmaf(xv.x, w0, acc[i]);
            acc[i] = fmaf(xv.y, w1, acc[i]);
            acc[i] = fmaf(xv.z, w2v, acc[i]);
            acc[i] = fmaf(xv.w, w3, acc[i]);
        }
    }
    #pragma unroll
    for (int i = 0; i < 16; ++i) {
        int n = nbase + iq * 16 + i;
        if (n < N_NODES) y[(size_t)n * 64 + h] = acc[i];
    }
}

// ---------------- per-graph node count ----------------
__global__ void k_cnt(const int* __restrict__ batch, float* __restrict__ cnt) {
    int n = blockIdx.x * 256 + threadIdx.x;
    if (n < N_NODES) atomicAdd(&cnt[batch[n]], 1.0f);
}

// ---------------- bn2 + relu + pooling (sum & max), run-length batched atomics ----------------
__global__ __launch_bounds__(256) void k_pool(const float* __restrict__ xp2,
        const float* __restrict__ scsh2, const int* __restrict__ batch,
        float* __restrict__ psum, unsigned int* __restrict__ pmax) {
    int tid = threadIdx.x;
    int h = tid & 63, q = tid >> 6;
    float sc = scsh2[h], sh = scsh2[64 + h];
    int base = blockIdx.x * 256;
    int curg = -1; float ls = 0.f, lm = 0.f;
    for (int j = 0; j < 64; ++j) {
        int r = base + j * 4 + q;
        if (r >= N_NODES) break;
        int g = batch[r];
        if (g != curg) {
            if (curg >= 0) {
                atomicAdd(&psum[curg * 64 + h], ls);
                atomicMax(&pmax[curg * 64 + h], __float_as_uint(lm));
            }
            curg = g; ls = 0.f; lm = 0.f;
        }
        float v = fmaxf(fmaf(xp2[(size_t)r * 64 + h], sc, sh), 0.f);
        ls += v; lm = fmaxf(lm, v);
    }
    if (curg >= 0) {
        atomicAdd(&psum[curg * 64 + h], ls);
        atomicMax(&pmax[curg * 64 + h], __float_as_uint(lm));
    }
}

// ---------------- classifier ----------------
__global__ void k_cls(const float* __restrict__ psum, const unsigned int* __restrict__ pmax,
                      const float* __restrict__ cnt, const float* __restrict__ Wc,
                      const float* __restrict__ bc, float* __restrict__ out) {
    int t = threadIdx.x;
    if (t >= NGRAPH * NC) return;
    int g = t / NC, c = t % NC;
    float invc = 1.f / fmaxf(cnt[g], 1.f);
    float acc = bc[c];
    #pragma unroll 8
    for (int j = 0; j < 64; ++j) {
        float s = psum[g * 64 + j];
        float mx = __uint_as_float(pmax[g * 64 + j]);
        acc = fmaf(s * invc, Wc[j * 3 + c], acc);
        acc = fmaf(mx, Wc[(64 + j) * 3 + c], acc);
        acc = fmaf(s, Wc[(128 + j) * 3 + c], acc);
    }
    out[g * NC + c] = acc;
}

extern "C" void kernel_launch(void* const* d_in, const int* in_sizes, int n_in,
                              void* d_out, int out_size, void* d_ws, size_t ws_size,
                              hipStream_t stream) {
    const float* x    = (const float*)d_in[0];
    const int*   ei   = (const int*)d_in[1];
    const int*   batch= (const int*)d_in[2];
    const float* Wexp = (const float*)d_in[3];
    const float* bexp = (const float*)d_in[4];
    const float* gW1  = (const float*)d_in[5];
    const float* gb1  = (const float*)d_in[6];
    const float* gW2  = (const float*)d_in[7];
    const float* gb2  = (const float*)d_in[8];
    const float* W2   = (const float*)d_in[9];
    // d_in[10] = b2: cancels inside bn2 (per-column constant shift)
    const float* bn1g = (const float*)d_in[11];
    const float* bn1b = (const float*)d_in[12];
    const float* bn2g = (const float*)d_in[13];
    const float* bn2b = (const float*)d_in[14];
    const float* clsW = (const float*)d_in[15];
    const float* clsb = (const float*)d_in[16];
    float* out = (float*)d_out;

    float* ws = (float*)d_ws;
    const size_t NN = N_NODES;
    float* deg_isqrt = ws;
    float* deg_inv   = ws + NN;
    float* gate      = ws + 2 * NN;      // N*3
    float* h1pre     = ws + 5 * NN;      // N*64
    float* xp        = ws + 69 * NN;     // N*128 (reused: y = first 64N, xp2 = next 64N)
    float* y         = xp;
    float* xp2       = xp + 64 * NN;
    float* stats     = ws + 197 * NN;
    float* sums1 = stats,        *scsh1 = stats + 128;
    float* sums2 = stats + 256,  *scsh2 = stats + 384;
    float* psum  = stats + 512;                            // G*64
    unsigned int* pmax = (unsigned int*)(stats + 512 + 4096);
    float* cnt   = stats + 512 + 8192;                     // G
    int* ideg      = (int*)(ws + 197 * NN + 16384);        // N (reused as cursor)
    int* row_start = ideg + NN;                            // N+1
    int* csr_src   = row_start + NN + 64;                  // E

    hipMemsetAsync(ideg, 0, NN * sizeof(int), stream);
    hipMemsetAsync(stats, 0, (512 + 8192 + 64) * sizeof(float), stream);

    k_degi<<<(N_EDGES + 255) / 256, 256, 0, stream>>>(ei + N_EDGES, ideg);
    k_scan<<<1, 1024, 0, stream>>>(ideg, row_start);
    k_deg_fin<<<(N_NODES + 255) / 256, 256, 0, stream>>>(ideg, deg_isqrt, deg_inv);
    hipMemsetAsync(ideg, 0, NN * sizeof(int), stream);   // ideg -> cursor
    k_fill<<<(N_EDGES + 255) / 256, 256, 0, stream>>>(ei, row_start, ideg, csr_src);

    k_gate<<<(N_NODES + 7) / 8, 256, 0, stream>>>(x, gW1, gb1, gW2, gb2, gate);
    k_gather<32><<<(N_NODES + 7) / 8, 256, 0, stream>>>(csr_src, row_start, deg_isqrt, deg_inv, x, xp);
    k_expert<<<(N_NODES + 31) / 32, 256, 0, stream>>>(xp, Wexp, bexp, gate, h1pre);
    k_stats<<<128, 256, 0, stream>>>(h1pre, sums1);
    k_statfin<<<1, 64, 0, stream>>>(sums1, bn1g, bn1b, scsh1);
    k_w2<<<(N_NODES + 63) / 64, 256, 0, stream>>>(h1pre, scsh1, W2, y);
    k_gather<16><<<(N_NODES + 15) / 16, 256, 0, stream>>>(csr_src, row_start, deg_isqrt, deg_inv, y, xp2);
    k_stats<<<128, 256, 0, stream>>>(xp2, sums2);
    k_statfin<<<1, 64, 0, stream>>>(sums2, bn2g, bn2b, scsh2);
    k_cnt<<<(N_NODES + 255) / 256, 256, 0, stream>>>(batch, cnt);
    k_pool<<<(N_NODES + 255) / 256, 256, 0, stream>>>(xp2, scsh2, batch, psum, pmax);
    k_cls<<<1, 256, 0, stream>>>(psum, pmax, cnt, clsW, clsb, out);
}

// Round 3
// 573.329 us; speedup vs baseline: 4.4318x; 1.3861x over previous
//
#include <hip/hip_runtime.h>

#define N_NODES 50000
#define N_EDGES 800000
#define F 128
#define HDIM 64
#define NE 3
#define NGRAPH 64
#define NC 3
#define BN_EPS 1e-5f

// ---------------- degree count (int atomics) ----------------
__global__ void k_degi(const int* __restrict__ dst, int* __restrict__ ideg) {
    int e = blockIdx.x * 256 + threadIdx.x;
    if (e < N_EDGES) atomicAdd(&ideg[dst[e]], 1);
}

__global__ void k_deg_fin(const int* __restrict__ ideg, float* __restrict__ deg_isqrt,
                          float* __restrict__ deg_inv) {
    int n = blockIdx.x * 256 + threadIdx.x;
    if (n < N_NODES) {
        float d = (float)ideg[n] + 1.0f;
        deg_isqrt[n] = rsqrtf(d);
        deg_inv[n] = 1.0f / d;
    }
}

// ---------------- exclusive scan of degrees -> row_start (single block) ----------------
__global__ __launch_bounds__(1024) void k_scan(const int* __restrict__ ideg,
                                               int* __restrict__ row_start) {
    __shared__ int wsums[16];
    __shared__ int s_carry;
    int tid = threadIdx.x;
    int lane = tid & 63, wid = tid >> 6;
    if (tid == 0) s_carry = 0;
    __syncthreads();
    for (int base = 0; base < N_NODES; base += 1024) {
        int i = base + tid;
        int v = (i < N_NODES) ? ideg[i] : 0;
        int x = v;
        #pragma unroll
        for (int off = 1; off < 64; off <<= 1) {
            int u = __shfl_up(x, off, 64);
            if (lane >= off) x += u;
        }
        if (lane == 63) wsums[wid] = x;
        __syncthreads();
        if (wid == 0) {
            int wv = (lane < 16) ? wsums[lane] : 0;
            #pragma unroll
            for (int off = 1; off < 16; off <<= 1) {
                int u = __shfl_up(wv, off, 64);
                if (lane >= off) wv += u;
            }
            if (lane < 16) wsums[lane] = wv;
        }
        __syncthreads();
        int carry = s_carry;
        int excl = carry + (wid > 0 ? wsums[wid - 1] : 0) + (x - v);
        if (i < N_NODES) row_start[i] = excl;
        __syncthreads();
        if (tid == 1023) s_carry = carry + wsums[15];
        __syncthreads();
    }
    if (tid == 0) row_start[N_NODES] = s_carry;
}

// ---------------- fill CSR (src only; slot via atomic cursor) ----------------
__global__ void k_fill(const int* __restrict__ ei, const int* __restrict__ row_start,
                       int* __restrict__ cursor, int* __restrict__ csr_src) {
    int e = blockIdx.x * 256 + threadIdx.x;
    if (e >= N_EDGES) return;
    int s = ei[e], d = ei[N_EDGES + e];
    int slot = atomicAdd(&cursor[d], 1);
    csr_src[row_start[d] + slot] = s;
}

// ---------------- gating MLP: softmax(relu(x@W1+b1)@W2+b2) ----------------
__global__ __launch_bounds__(256) void k_gate(const float* __restrict__ x,
        const float* __restrict__ W1, const float* __restrict__ b1,
        const float* __restrict__ W2, const float* __restrict__ b2,
        float* __restrict__ gate) {
    __shared__ float hs[8][32];
    int tid = threadIdx.x;
    int grp = tid >> 5, j = tid & 31;
    int n = blockIdx.x * 8 + grp;
    float acc = b1[j];
    if (n < N_NODES) {
        const float* xr = x + (size_t)n * F;
        #pragma unroll 8
        for (int k = 0; k < F; ++k) acc = fmaf(xr[k], W1[k * 32 + j], acc);
    }
    hs[grp][j] = fmaxf(acc, 0.f);
    __syncthreads();
    if (tid < 8) {
        int nn = blockIdx.x * 8 + tid;
        if (nn < N_NODES) {
            float l0 = b2[0], l1 = b2[1], l2 = b2[2];
            #pragma unroll
            for (int k = 0; k < 32; ++k) {
                float h = hs[tid][k];
                l0 = fmaf(h, W2[k * 3 + 0], l0);
                l1 = fmaf(h, W2[k * 3 + 1], l1);
                l2 = fmaf(h, W2[k * 3 + 2], l2);
            }
            float m = fmaxf(l0, fmaxf(l1, l2));
            float e0 = __expf(l0 - m), e1 = __expf(l1 - m), e2 = __expf(l2 - m);
            float inv = 1.f / (e0 + e1 + e2);
            gate[nn * 3 + 0] = e0 * inv;
            gate[nn * 3 + 1] = e1 * inv;
            gate[nn * 3 + 2] = e2 * inv;
        }
    }
}

// ---------------- GCN prop via CSR gather (self-loop folded in) ----------------
template<int F4>   // row width in float4: 32 (F=128) or 16 (H=64)
__global__ __launch_bounds__(256) void k_gather(const int* __restrict__ csr_src,
        const int* __restrict__ row_start, const float* __restrict__ deg_isqrt,
        const float* __restrict__ deg_inv, const float* __restrict__ hin,
        float* __restrict__ out) {
    constexpr int GPB = 256 / F4;
    int lane = threadIdx.x % F4;
    int grp  = threadIdx.x / F4;
    int n = blockIdx.x * GPB + grp;
    if (n >= N_NODES) return;
    const float4* hin4 = (const float4*)hin;
    int beg = row_start[n], end = row_start[n + 1];
    float isq_n = deg_isqrt[n];
    float di = deg_inv[n];
    float4 sv = hin4[(size_t)n * F4 + lane];
    float ax = sv.x * di, ay = sv.y * di, az = sv.z * di, aw = sv.w * di;
    int j = beg;
    for (; j + 1 < end; j += 2) {
        int s0 = csr_src[j], s1 = csr_src[j + 1];
        float m0 = isq_n * deg_isqrt[s0];
        float m1 = isq_n * deg_isqrt[s1];
        float4 v0 = hin4[(size_t)s0 * F4 + lane];
        float4 v1 = hin4[(size_t)s1 * F4 + lane];
        ax = fmaf(m0, v0.x, ax); ay = fmaf(m0, v0.y, ay);
        az = fmaf(m0, v0.z, az); aw = fmaf(m0, v0.w, aw);
        ax = fmaf(m1, v1.x, ax); ay = fmaf(m1, v1.y, ay);
        az = fmaf(m1, v1.z, az); aw = fmaf(m1, v1.w, aw);
    }
    if (j < end) {
        int s0 = csr_src[j];
        float m0 = isq_n * deg_isqrt[s0];
        float4 v0 = hin4[(size_t)s0 * F4 + lane];
        ax = fmaf(m0, v0.x, ax); ay = fmaf(m0, v0.y, ay);
        az = fmaf(m0, v0.z, az); aw = fmaf(m0, v0.w, aw);
    }
    ((float4*)out)[(size_t)n * F4 + lane] = make_float4(ax, ay, az, aw);
}

// ---------------- experts + gated combine (W in LDS, x direct from global) ----------------
__global__ __launch_bounds__(256) void k_expert(const float* __restrict__ xp,
        const float* __restrict__ Wexp, const float* __restrict__ bexp,
        const float* __restrict__ gate, float* __restrict__ h1pre) {
    __shared__ float wsd[128 * 64];   // 32 KB, one expert at a time
    int tid = threadIdx.x;
    int h = tid & 63, iq = tid >> 6;
    int n0 = blockIdx.x * 32 + iq * 8;
    const float4* xr[8];
    #pragma unroll
    for (int i = 0; i < 8; ++i) {
        int n = n0 + i; if (n >= N_NODES) n = N_NODES - 1;
        xr[i] = (const float4*)xp + (size_t)n * 32;
    }
    float comb[8];
    #pragma unroll
    for (int i = 0; i < 8; ++i) comb[i] = 0.f;
    for (int e = 0; e < NE; ++e) {
        __syncthreads();
        const float4* wsrc = (const float4*)(Wexp + (size_t)e * F * HDIM);
        for (int i = tid; i < 128 * 16; i += 256) ((float4*)wsd)[i] = wsrc[i];
        __syncthreads();
        float be = bexp[e * HDIM + h];
        float acc[8];
        #pragma unroll
        for (int i = 0; i < 8; ++i) acc[i] = 0.f;
        for (int k4 = 0; k4 < 32; ++k4) {
            float w0 = wsd[(k4 * 4 + 0) * 64 + h];
            float w1 = wsd[(k4 * 4 + 1) * 64 + h];
            float w2 = wsd[(k4 * 4 + 2) * 64 + h];
            float w3 = wsd[(k4 * 4 + 3) * 64 + h];
            #pragma unroll
            for (int i = 0; i < 8; ++i) {
                float4 xv = xr[i][k4];
                acc[i] = fmaf(xv.x, w0, acc[i]);
                acc[i] = fmaf(xv.y, w1, acc[i]);
                acc[i] = fmaf(xv.z, w2, acc[i]);
                acc[i] = fmaf(xv.w, w3, acc[i]);
            }
        }
        #pragma unroll
        for (int i = 0; i < 8; ++i) {
            int n = n0 + i;
            float gg = (n < N_NODES) ? gate[n * 3 + e] : 0.f;
            comb[i] = fmaf(gg, acc[i] + be, comb[i]);
        }
    }
    #pragma unroll
    for (int i = 0; i < 8; ++i) {
        int n = n0 + i;
        if (n < N_NODES) h1pre[(size_t)n * HDIM + h] = comb[i];
    }
}

// ---------------- column sums / sumsq for batchnorm ----------------
__global__ __launch_bounds__(256) void k_stats(const float* __restrict__ hm, float* __restrict__ sums) {
    int tid = threadIdx.x;
    int c = tid & 63, q = tid >> 6;
    float s = 0.f, s2 = 0.f;
    for (int r = blockIdx.x * 4 + q; r < N_NODES; r += gridDim.x * 4) {
        float v = hm[(size_t)r * 64 + c];
        s += v; s2 = fmaf(v, v, s2);
    }
    __shared__ float red[2][4][64];
    red[0][q][c] = s; red[1][q][c] = s2;
    __syncthreads();
    if (q == 0) {
        s  = red[0][0][c] + red[0][1][c] + red[0][2][c] + red[0][3][c];
        s2 = red[1][0][c] + red[1][1][c] + red[1][2][c] + red[1][3][c];
        atomicAdd(&sums[c], s);
        atomicAdd(&sums[64 + c], s2);
    }
}

__global__ void k_statfin(const float* __restrict__ sums, const float* __restrict__ g,
                          const float* __restrict__ b, float* __restrict__ scsh) {
    int c = threadIdx.x;  // 64 threads
    float mu = sums[c] * (1.0f / N_NODES);
    float var = sums[64 + c] * (1.0f / N_NODES) - mu * mu;
    float rs = rsqrtf(var + BN_EPS);
    float sc = rs * g[c];
    scsh[c] = sc;
    scsh[64 + c] = b[c] - mu * sc;
}

// ---------------- bn1 + relu fused into h1 @ W2 ----------------
__global__ __launch_bounds__(256) void k_w2(const float* __restrict__ h1pre,
        const float* __restrict__ scsh, const float* __restrict__ W2, float* __restrict__ y) {
    __shared__ float4 hsd[64 * 16];  // 16 KB
    __shared__ float  wsd[64 * 64];  // 16 KB
    int tid = threadIdx.x;
    int nbase = blockIdx.x * 64;
    for (int i = tid; i < 64 * 16; i += 256) ((float4*)wsd)[i] = ((const float4*)W2)[i];
    for (int i = tid; i < 64 * 16; i += 256) {
        int r = i >> 4, c = i & 15;
        int n = nbase + r; if (n >= N_NODES) n = N_NODES - 1;
        float4 v  = ((const float4*)h1pre)[(size_t)n * 16 + c];
        float4 sc = ((const float4*)scsh)[c];
        float4 sh = ((const float4*)scsh)[16 + c];
        v.x = fmaxf(fmaf(v.x, sc.x, sh.x), 0.f);
        v.y = fmaxf(fmaf(v.y, sc.y, sh.y), 0.f);
        v.z = fmaxf(fmaf(v.z, sc.z, sh.z), 0.f);
        v.w = fmaxf(fmaf(v.w, sc.w, sh.w), 0.f);
        hsd[i] = v;
    }
    __syncthreads();
    int h = tid & 63, iq = tid >> 6;
    float acc[16];
    #pragma unroll
    for (int i = 0; i < 16; ++i) acc[i] = 0.f;
    for (int k4 = 0; k4 < 16; ++k4) {
        float w0 = wsd[(k4 * 4 + 0) * 64 + h];
        float w1 = wsd[(k4 * 4 + 1) * 64 + h];
        float w2v = wsd[(k4 * 4 + 2) * 64 + h];
        float w3 = wsd[(k4 * 4 + 3) * 64 + h];
        #pragma unroll
        for (int i = 0; i < 16; ++i) {
            float4 xv = hsd[(iq * 16 + i) * 16 + k4];
            acc[i] = fmaf(xv.x, w0, acc[i]);
            acc[i] = fmaf(xv.y, w1, acc[i]);
            acc[i] = fmaf(xv.z, w2v, acc[i]);
            acc[i] = fmaf(xv.w, w3, acc[i]);
        }
    }
    #pragma unroll
    for (int i = 0; i < 16; ++i) {
        int n = nbase + iq * 16 + i;
        if (n < N_NODES) y[(size_t)n * 64 + h] = acc[i];
    }
}

// ---------------- bn2 + relu + pooling (sum & max), run-length batched atomics ----------------
__global__ __launch_bounds__(256) void k_pool(const float* __restrict__ xp2,
        const float* __restrict__ scsh2, const int* __restrict__ batch,
        float* __restrict__ psum, unsigned int* __restrict__ pmax) {
    int tid = threadIdx.x;
    int h = tid & 63, q = tid >> 6;
    float sc = scsh2[h], sh = scsh2[64 + h];
    int base = blockIdx.x * 256;
    int curg = -1; float ls = 0.f, lm = 0.f;
    for (int j = 0; j < 64; ++j) {
        int r = base + j * 4 + q;
        if (r >= N_NODES) break;
        int g = batch[r];
        if (g != curg) {
            if (curg >= 0) {
                atomicAdd(&psum[curg * 64 + h], ls);
                atomicMax(&pmax[curg * 64 + h], __float_as_uint(lm));
            }
            curg = g; ls = 0.f; lm = 0.f;
        }
        float v = fmaxf(fmaf(xp2[(size_t)r * 64 + h], sc, sh), 0.f);
        ls += v; lm = fmaxf(lm, v);
    }
    if (curg >= 0) {
        atomicAdd(&psum[curg * 64 + h], ls);
        atomicMax(&pmax[curg * 64 + h], __float_as_uint(lm));
    }
}

// ---------------- classifier (per-graph count via binary search on sorted batch) ----------------
__global__ void k_cls(const float* __restrict__ psum, const unsigned int* __restrict__ pmax,
                      const int* __restrict__ batch, const float* __restrict__ Wc,
                      const float* __restrict__ bc, float* __restrict__ out) {
    int t = threadIdx.x;
    if (t >= NGRAPH * NC) return;
    int g = t / NC, c = t % NC;
    // count of nodes with batch[i] == g  (batch is sorted ascending)
    int lo = 0, hi = N_NODES;
    while (lo < hi) { int mid = (lo + hi) >> 1; if (batch[mid] < g) lo = mid + 1; else hi = mid; }
    int lb = lo;
    hi = N_NODES;
    while (lo < hi) { int mid = (lo + hi) >> 1; if (batch[mid] < g + 1) lo = mid + 1; else hi = mid; }
    float cnt = (float)(lo - lb);
    float invc = 1.f / fmaxf(cnt, 1.f);
    float acc = bc[c];
    #pragma unroll 8
    for (int j = 0; j < 64; ++j) {
        float s = psum[g * 64 + j];
        float mx = __uint_as_float(pmax[g * 64 + j]);
        acc = fmaf(s * invc, Wc[j * 3 + c], acc);
        acc = fmaf(mx, Wc[(64 + j) * 3 + c], acc);
        acc = fmaf(s, Wc[(128 + j) * 3 + c], acc);
    }
    out[g * NC + c] = acc;
}

extern "C" void kernel_launch(void* const* d_in, const int* in_sizes, int n_in,
                              void* d_out, int out_size, void* d_ws, size_t ws_size,
                              hipStream_t stream) {
    const float* x    = (const float*)d_in[0];
    const int*   ei   = (const int*)d_in[1];
    const int*   batch= (const int*)d_in[2];
    const float* Wexp = (const float*)d_in[3];
    const float* bexp = (const float*)d_in[4];
    const float* gW1  = (const float*)d_in[5];
    const float* gb1  = (const float*)d_in[6];
    const float* gW2  = (const float*)d_in[7];
    const float* gb2  = (const float*)d_in[8];
    const float* W2   = (const float*)d_in[9];
    // d_in[10] = b2: cancels inside bn2 (per-column constant shift)
    const float* bn1g = (const float*)d_in[11];
    const float* bn1b = (const float*)d_in[12];
    const float* bn2g = (const float*)d_in[13];
    const float* bn2b = (const float*)d_in[14];
    const float* clsW = (const float*)d_in[15];
    const float* clsb = (const float*)d_in[16];
    float* out = (float*)d_out;

    float* ws = (float*)d_ws;
    const size_t NN = N_NODES;
    float* deg_isqrt = ws;
    float* deg_inv   = ws + NN;
    float* gate      = ws + 2 * NN;      // N*3
    float* h1pre     = ws + 5 * NN;      // N*64
    float* xp        = ws + 69 * NN;     // N*128 (reused: y = first 64N, xp2 = next 64N)
    float* y         = xp;
    float* xp2       = xp + 64 * NN;
    float* stats     = ws + 197 * NN;
    float* sums1 = stats,        *scsh1 = stats + 128;
    float* sums2 = stats + 256,  *scsh2 = stats + 384;
    float* psum  = stats + 512;                            // G*64
    unsigned int* pmax = (unsigned int*)(stats + 512 + 4096);
    int* ideg      = (int*)(ws + 197 * NN + 16384);        // N (reused as cursor)
    int* row_start = ideg + NN;                            // N+1
    int* csr_src   = row_start + NN + 64;                  // E

    hipMemsetAsync(ideg, 0, NN * sizeof(int), stream);
    hipMemsetAsync(stats, 0, (512 + 8192) * sizeof(float), stream);

    k_degi<<<(N_EDGES + 255) / 256, 256, 0, stream>>>(ei + N_EDGES, ideg);
    k_scan<<<1, 1024, 0, stream>>>(ideg, row_start);
    k_deg_fin<<<(N_NODES + 255) / 256, 256, 0, stream>>>(ideg, deg_isqrt, deg_inv);
    hipMemsetAsync(ideg, 0, NN * sizeof(int), stream);   // ideg -> cursor
    k_fill<<<(N_EDGES + 255) / 256, 256, 0, stream>>>(ei, row_start, ideg, csr_src);

    k_gate<<<(N_NODES + 7) / 8, 256, 0, stream>>>(x, gW1, gb1, gW2, gb2, gate);
    k_gather<32><<<(N_NODES + 7) / 8, 256, 0, stream>>>(csr_src, row_start, deg_isqrt, deg_inv, x, xp);
    k_expert<<<(N_NODES + 31) / 32, 256, 0, stream>>>(xp, Wexp, bexp, gate, h1pre);
    k_stats<<<128, 256, 0, stream>>>(h1pre, sums1);
    k_statfin<<<1, 64, 0, stream>>>(sums1, bn1g, bn1b, scsh1);
    k_w2<<<(N_NODES + 63) / 64, 256, 0, stream>>>(h1pre, scsh1, W2, y);
    k_gather<16><<<(N_NODES + 15) / 16, 256, 0, stream>>>(csr_src, row_start, deg_isqrt, deg_inv, y, xp2);
    k_stats<<<128, 256, 0, stream>>>(xp2, sums2);
    k_statfin<<<1, 64, 0, stream>>>(sums2, bn2g, bn2b, scsh2);
    k_pool<<<(N_NODES + 255) / 256, 256, 0, stream>>>(xp2, scsh2, batch, psum, pmax);
    k_cls<<<1, 256, 0, stream>>>(psum, pmax, batch, clsW, clsb, out);
}

// Round 4
// 436.007 us; speedup vs baseline: 5.8276x; 1.3150x over previous
//
#include <hip/hip_runtime.h>

#define N_NODES 50000
#define N_EDGES 800000
#define F 128
#define HDIM 64
#define NE 3
#define NGRAPH 64
#define NC 3
#define BN_EPS 1e-5f
#define NB_SCAN 49   // ceil(N_NODES / 1024)

// ---------------- degree count (int atomics) ----------------
__global__ void k_degi(const int* __restrict__ dst, int* __restrict__ ideg) {
    int e = blockIdx.x * 256 + threadIdx.x;
    if (e < N_EDGES) atomicAdd(&ideg[dst[e]], 1);
}

// ---------------- scan stage 1: per-block scan + deg_isqrt + cursor zero ----------------
__global__ __launch_bounds__(1024) void k_scan1(const int* __restrict__ ideg,
        int* __restrict__ row_start, int* __restrict__ btot,
        float* __restrict__ deg_isqrt, int* __restrict__ cursor) {
    __shared__ int wsums[16];
    int tid = threadIdx.x, lane = tid & 63, wid = tid >> 6;
    int i = blockIdx.x * 1024 + tid;
    int v = (i < N_NODES) ? ideg[i] : 0;
    if (i < N_NODES) {
        deg_isqrt[i] = rsqrtf((float)v + 1.0f);
        cursor[i] = 0;
    }
    int xsc = v;
    #pragma unroll
    for (int off = 1; off < 64; off <<= 1) {
        int u = __shfl_up(xsc, off, 64);
        if (lane >= off) xsc += u;
    }
    if (lane == 63) wsums[wid] = xsc;
    __syncthreads();
    if (wid == 0) {
        int wv = (lane < 16) ? wsums[lane] : 0;
        #pragma unroll
        for (int off = 1; off < 16; off <<= 1) {
            int u = __shfl_up(wv, off, 64);
            if (lane >= off) wv += u;
        }
        if (lane < 16) wsums[lane] = wv;
    }
    __syncthreads();
    int excl = (wid > 0 ? wsums[wid - 1] : 0) + (xsc - v);
    if (i < N_NODES) row_start[i] = excl;
    if (tid == 0) btot[blockIdx.x] = wsums[15];
}

// ---------------- scan stage 2: scan block totals (1 wave) ----------------
__global__ void k_scan2(const int* __restrict__ btot, int* __restrict__ boff,
                        int* __restrict__ row_start) {
    int lane = threadIdx.x;  // 64 threads
    int v = (lane < NB_SCAN) ? btot[lane] : 0;
    int xsc = v;
    #pragma unroll
    for (int off = 1; off < 64; off <<= 1) {
        int u = __shfl_up(xsc, off, 64);
        if (lane >= off) xsc += u;
    }
    if (lane < NB_SCAN) boff[lane] = xsc - v;
    if (lane == 63) row_start[N_NODES] = xsc;
}

// ---------------- scan stage 3: add block offsets ----------------
__global__ __launch_bounds__(1024) void k_scan3(int* __restrict__ row_start,
                                                const int* __restrict__ boff) {
    int i = blockIdx.x * 1024 + threadIdx.x;
    if (i < N_NODES) row_start[i] += boff[blockIdx.x];
}

// ---------------- fill CSR (src only; slot via atomic cursor) ----------------
__global__ void k_fill(const int* __restrict__ ei, const int* __restrict__ row_start,
                       int* __restrict__ cursor, int* __restrict__ csr_src) {
    int e = blockIdx.x * 256 + threadIdx.x;
    if (e >= N_EDGES) return;
    int s = ei[e], d = ei[N_EDGES + e];
    int slot = atomicAdd(&cursor[d], 1);
    csr_src[row_start[d] + slot] = s;
}

// ---------------- gating MLP + x' = x * isq side-output ----------------
__global__ __launch_bounds__(256) void k_gate(const float* __restrict__ x,
        const float* __restrict__ deg_isqrt,
        const float* __restrict__ W1, const float* __restrict__ b1,
        const float* __restrict__ W2, const float* __restrict__ b2,
        float* __restrict__ gate, float* __restrict__ xprime) {
    __shared__ float4 xls[8][32];
    __shared__ float hs[8][32];
    int tid = threadIdx.x;
    int grp = tid >> 5, j = tid & 31;
    int n = blockIdx.x * 8 + grp;
    int nc = (n < N_NODES) ? n : N_NODES - 1;
    float4 v = ((const float4*)x)[(size_t)nc * 32 + j];
    xls[grp][j] = v;
    float si = deg_isqrt[nc];
    if (n < N_NODES)
        ((float4*)xprime)[(size_t)n * 32 + j] =
            make_float4(v.x * si, v.y * si, v.z * si, v.w * si);
    __syncthreads();
    float acc = b1[j];
    #pragma unroll 8
    for (int k4 = 0; k4 < 32; ++k4) {
        float4 xv = xls[grp][k4];
        acc = fmaf(xv.x, W1[(k4 * 4 + 0) * 32 + j], acc);
        acc = fmaf(xv.y, W1[(k4 * 4 + 1) * 32 + j], acc);
        acc = fmaf(xv.z, W1[(k4 * 4 + 2) * 32 + j], acc);
        acc = fmaf(xv.w, W1[(k4 * 4 + 3) * 32 + j], acc);
    }
    hs[grp][j] = fmaxf(acc, 0.f);
    __syncthreads();
    if (tid < 8) {
        int nn = blockIdx.x * 8 + tid;
        if (nn < N_NODES) {
            float l0 = b2[0], l1 = b2[1], l2 = b2[2];
            #pragma unroll
            for (int k = 0; k < 32; ++k) {
                float h = hs[tid][k];
                l0 = fmaf(h, W2[k * 3 + 0], l0);
                l1 = fmaf(h, W2[k * 3 + 1], l1);
                l2 = fmaf(h, W2[k * 3 + 2], l2);
            }
            float m = fmaxf(l0, fmaxf(l1, l2));
            float e0 = __expf(l0 - m), e1 = __expf(l1 - m), e2 = __expf(l2 - m);
            float inv = 1.f / (e0 + e1 + e2);
            gate[nn * 3 + 0] = e0 * inv;
            gate[nn * 3 + 1] = e1 * inv;
            gate[nn * 3 + 2] = e2 * inv;
        }
    }
}

// ---------------- GCN prop on pre-scaled features: out_n = isq_n * (h'_n + sum_{j->n} h'_src) ----------------
template<int F4>   // row width in float4: 32 (F=128) or 16 (H=64)
__global__ __launch_bounds__(256) void k_gsum(const int* __restrict__ csr_src,
        const int* __restrict__ row_start, const float* __restrict__ deg_isqrt,
        const float* __restrict__ hin, float* __restrict__ out) {
    constexpr int GPB = 256 / F4;
    int lane = threadIdx.x % F4;
    int grp  = threadIdx.x / F4;
    int n = blockIdx.x * GPB + grp;
    if (n >= N_NODES) return;
    const float4* hin4 = (const float4*)hin;
    int beg = row_start[n], end = row_start[n + 1];
    float4 sv = hin4[(size_t)n * F4 + lane];
    float ax = sv.x, ay = sv.y, az = sv.z, aw = sv.w;
    int j = beg;
    for (; j + 1 < end; j += 2) {
        int s0 = csr_src[j], s1 = csr_src[j + 1];
        float4 v0 = hin4[(size_t)s0 * F4 + lane];
        float4 v1 = hin4[(size_t)s1 * F4 + lane];
        ax += v0.x; ay += v0.y; az += v0.z; aw += v0.w;
        ax += v1.x; ay += v1.y; az += v1.z; aw += v1.w;
    }
    if (j < end) {
        int s0 = csr_src[j];
        float4 v0 = hin4[(size_t)s0 * F4 + lane];
        ax += v0.x; ay += v0.y; az += v0.z; aw += v0.w;
    }
    float s = deg_isqrt[n];
    ((float4*)out)[(size_t)n * F4 + lane] = make_float4(ax * s, ay * s, az * s, aw * s);
}

// ---------------- experts + gated combine (x tile AND W tile in LDS) ----------------
__global__ __launch_bounds__(256) void k_expert(const float* __restrict__ xp,
        const float* __restrict__ Wexp, const float* __restrict__ bexp,
        const float* __restrict__ gate, float* __restrict__ h1pre) {
    __shared__ float4 xs[32 * 32];   // 16 KB  [node][k4]
    __shared__ float  wsd[128 * 64]; // 32 KB  [k][h], one expert at a time
    int tid = threadIdx.x;
    int nbase = blockIdx.x * 32;
    for (int i = tid; i < 32 * 32; i += 256) {
        int r = i >> 5, c = i & 31;
        int n = nbase + r; if (n >= N_NODES) n = N_NODES - 1;
        xs[i] = ((const float4*)xp)[(size_t)n * 32 + c];
    }
    int h = tid & 63, iq = tid >> 6;
    int n0 = nbase + iq * 8;
    float comb[8];
    #pragma unroll
    for (int i = 0; i < 8; ++i) comb[i] = 0.f;
    for (int e = 0; e < NE; ++e) {
        __syncthreads();
        const float4* wsrc = (const float4*)(Wexp + (size_t)e * F * HDIM);
        for (int i = tid; i < 128 * 16; i += 256) ((float4*)wsd)[i] = wsrc[i];
        __syncthreads();
        float be = bexp[e * HDIM + h];
        float acc[8];
        #pragma unroll
        for (int i = 0; i < 8; ++i) acc[i] = 0.f;
        #pragma unroll 4
        for (int k4 = 0; k4 < 32; ++k4) {
            float w0 = wsd[(k4 * 4 + 0) * 64 + h];
            float w1 = wsd[(k4 * 4 + 1) * 64 + h];
            float w2 = wsd[(k4 * 4 + 2) * 64 + h];
            float w3 = wsd[(k4 * 4 + 3) * 64 + h];
            #pragma unroll
            for (int i = 0; i < 8; ++i) {
                float4 xv = xs[(iq * 8 + i) * 32 + k4];
                acc[i] = fmaf(xv.x, w0, acc[i]);
                acc[i] = fmaf(xv.y, w1, acc[i]);
                acc[i] = fmaf(xv.z, w2, acc[i]);
                acc[i] = fmaf(xv.w, w3, acc[i]);
            }
        }
        #pragma unroll
        for (int i = 0; i < 8; ++i) {
            int n = n0 + i;
            float gg = (n < N_NODES) ? gate[n * 3 + e] : 0.f;
            comb[i] = fmaf(gg, acc[i] + be, comb[i]);
        }
    }
    #pragma unroll
    for (int i = 0; i < 8; ++i) {
        int n = n0 + i;
        if (n < N_NODES) h1pre[(size_t)n * HDIM + h] = comb[i];
    }
}

// ---------------- column sums / sumsq for batchnorm ----------------
__global__ __launch_bounds__(256) void k_stats(const float* __restrict__ hm, float* __restrict__ sums) {
    int tid = threadIdx.x;
    int c = tid & 63, q = tid >> 6;
    float s = 0.f, s2 = 0.f;
    for (int r = blockIdx.x * 4 + q; r < N_NODES; r += gridDim.x * 4) {
        float v = hm[(size_t)r * 64 + c];
        s += v; s2 = fmaf(v, v, s2);
    }
    __shared__ float red[2][4][64];
    red[0][q][c] = s; red[1][q][c] = s2;
    __syncthreads();
    if (q == 0) {
        s  = red[0][0][c] + red[0][1][c] + red[0][2][c] + red[0][3][c];
        s2 = red[1][0][c] + red[1][1][c] + red[1][2][c] + red[1][3][c];
        atomicAdd(&sums[c], s);
        atomicAdd(&sums[64 + c], s2);
    }
}

__global__ void k_statfin(const float* __restrict__ sums, const float* __restrict__ g,
                          const float* __restrict__ b, float* __restrict__ scsh) {
    int c = threadIdx.x;  // 64 threads
    float mu = sums[c] * (1.0f / N_NODES);
    float var = sums[64 + c] * (1.0f / N_NODES) - mu * mu;
    float rs = rsqrtf(var + BN_EPS);
    float sc = rs * g[c];
    scsh[c] = sc;
    scsh[64 + c] = b[c] - mu * sc;
}

// ---------------- bn1 + relu fused into h1 @ W2, epilogue scales by isq -> y' ----------------
__global__ __launch_bounds__(256) void k_w2(const float* __restrict__ h1pre,
        const float* __restrict__ scsh, const float* __restrict__ W2,
        const float* __restrict__ deg_isqrt, float* __restrict__ y) {
    __shared__ float4 hsd[64 * 16];  // 16 KB
    __shared__ float  wsd[64 * 64];  // 16 KB
    int tid = threadIdx.x;
    int nbase = blockIdx.x * 64;
    for (int i = tid; i < 64 * 16; i += 256) ((float4*)wsd)[i] = ((const float4*)W2)[i];
    for (int i = tid; i < 64 * 16; i += 256) {
        int r = i >> 4, c = i & 15;
        int n = nbase + r; if (n >= N_NODES) n = N_NODES - 1;
        float4 v  = ((const float4*)h1pre)[(size_t)n * 16 + c];
        float4 sc = ((const float4*)scsh)[c];
        float4 sh = ((const float4*)scsh)[16 + c];
        v.x = fmaxf(fmaf(v.x, sc.x, sh.x), 0.f);
        v.y = fmaxf(fmaf(v.y, sc.y, sh.y), 0.f);
        v.z = fmaxf(fmaf(v.z, sc.z, sh.z), 0.f);
        v.w = fmaxf(fmaf(v.w, sc.w, sh.w), 0.f);
        hsd[i] = v;
    }
    __syncthreads();
    int h = tid & 63, iq = tid >> 6;
    float acc[16];
    #pragma unroll
    for (int i = 0; i < 16; ++i) acc[i] = 0.f;
    for (int k4 = 0; k4 < 16; ++k4) {
        float w0 = wsd[(k4 * 4 + 0) * 64 + h];
        float w1 = wsd[(k4 * 4 + 1) * 64 + h];
        float w2v = wsd[(k4 * 4 + 2) * 64 + h];
        float w3 = wsd[(k4 * 4 + 3) * 64 + h];
        #pragma unroll
        for (int i = 0; i < 16; ++i) {
            float4 xv = hsd[(iq * 16 + i) * 16 + k4];
            acc[i] = fmaf(xv.x, w0, acc[i]);
            acc[i] = fmaf(xv.y, w1, acc[i]);
            acc[i] = fmaf(xv.z, w2v, acc[i]);
            acc[i] = fmaf(xv.w, w3, acc[i]);
        }
    }
    #pragma unroll
    for (int i = 0; i < 16; ++i) {
        int n = nbase + iq * 16 + i;
        if (n < N_NODES) y[(size_t)n * 64 + h] = acc[i] * deg_isqrt[n];
    }
}

// ---------------- bn2 + relu + pooling (sum & max), run-length batched atomics ----------------
__global__ __launch_bounds__(256) void k_pool(const float* __restrict__ xp2,
        const float* __restrict__ scsh2, const int* __restrict__ batch,
        float* __restrict__ psum, unsigned int* __restrict__ pmax) {
    int tid = threadIdx.x;
    int h = tid & 63, q = tid >> 6;
    float sc = scsh2[h], sh = scsh2[64 + h];
    int base = blockIdx.x * 256;
    int curg = -1; float ls = 0.f, lm = 0.f;
    for (int j = 0; j < 64; ++j) {
        int r = base + j * 4 + q;
        if (r >= N_NODES) break;
        int g = batch[r];
        if (g != curg) {
            if (curg >= 0) {
                atomicAdd(&psum[curg * 64 + h], ls);
                atomicMax(&pmax[curg * 64 + h], __float_as_uint(lm));
            }
            curg = g; ls = 0.f; lm = 0.f;
        }
        float v = fmaxf(fmaf(xp2[(size_t)r * 64 + h], sc, sh), 0.f);
        ls += v; lm = fmaxf(lm, v);
    }
    if (curg >= 0) {
        atomicAdd(&psum[curg * 64 + h], ls);
        atomicMax(&pmax[curg * 64 + h], __float_as_uint(lm));
    }
}

// ---------------- classifier (per-graph count via binary search on sorted batch) ----------------
__global__ void k_cls(const float* __restrict__ psum, const unsigned int* __restrict__ pmax,
                      const int* __restrict__ batch, const float* __restrict__ Wc,
                      const float* __restrict__ bc, float* __restrict__ out) {
    int t = threadIdx.x;
    if (t >= NGRAPH * NC) return;
    int g = t / NC, c = t % NC;
    int lo = 0, hi = N_NODES;
    while (lo < hi) { int mid = (lo + hi) >> 1; if (batch[mid] < g) lo = mid + 1; else hi = mid; }
    int lb = lo;
    hi = N_NODES;
    while (lo < hi) { int mid = (lo + hi) >> 1; if (batch[mid] < g + 1) lo = mid + 1; else hi = mid; }
    float cnt = (float)(lo - lb);
    float invc = 1.f / fmaxf(cnt, 1.f);
    float acc = bc[c];
    #pragma unroll 8
    for (int j = 0; j < 64; ++j) {
        float s = psum[g * 64 + j];
        float mx = __uint_as_float(pmax[g * 64 + j]);
        acc = fmaf(s * invc, Wc[j * 3 + c], acc);
        acc = fmaf(mx, Wc[(64 + j) * 3 + c], acc);
        acc = fmaf(s, Wc[(128 + j) * 3 + c], acc);
    }
    out[g * NC + c] = acc;
}

extern "C" void kernel_launch(void* const* d_in, const int* in_sizes, int n_in,
                              void* d_out, int out_size, void* d_ws, size_t ws_size,
                              hipStream_t stream) {
    const float* x    = (const float*)d_in[0];
    const int*   ei   = (const int*)d_in[1];
    const int*   batch= (const int*)d_in[2];
    const float* Wexp = (const float*)d_in[3];
    const float* bexp = (const float*)d_in[4];
    const float* gW1  = (const float*)d_in[5];
    const float* gb1  = (const float*)d_in[6];
    const float* gW2  = (const float*)d_in[7];
    const float* gb2  = (const float*)d_in[8];
    const float* W2   = (const float*)d_in[9];
    // d_in[10] = b2: cancels inside bn2 (per-column constant shift)
    const float* bn1g = (const float*)d_in[11];
    const float* bn1b = (const float*)d_in[12];
    const float* bn2g = (const float*)d_in[13];
    const float* bn2b = (const float*)d_in[14];
    const float* clsW = (const float*)d_in[15];
    const float* clsb = (const float*)d_in[16];
    float* out = (float*)d_out;

    float* ws = (float*)d_ws;
    const size_t NN = N_NODES;
    float* deg_isqrt = ws;                       // N
    int*   cursor    = (int*)(ws + NN);          // N
    float* gate      = ws + 2 * NN;              // 3N
    float* xprime    = ws + 5 * NN;              // 128N (dead after k_gsum<32>)
    float* h1pre     = ws + 5 * NN;              // 64N  (overlays dead xprime)
    float* xp        = ws + 133 * NN;            // 128N (dead after k_expert)
    float* xp2       = ws + 133 * NN;            // 64N  (overlays dead xp, 1st half)
    float* yprime    = ws + 197 * NN;            // 64N  (overlays dead xp, 2nd half)
    float* stats     = ws + 261 * NN;
    float* sums1 = stats;        float* scsh1 = stats + 128;
    float* sums2 = stats + 256;  float* scsh2 = stats + 384;
    float* psum  = stats + 512;                              // G*64
    unsigned int* pmax = (unsigned int*)(stats + 512 + 4096);
    int* ideg      = (int*)(ws + 261 * NN + 16384);          // N
    int* row_start = ideg + NN;                              // N+1
    int* btot      = row_start + NN + 8;                     // 64
    int* boff      = btot + 64;                              // 64
    int* csr_src   = boff + 64;                              // E

    hipMemsetAsync(ideg, 0, NN * sizeof(int), stream);
    hipMemsetAsync(stats, 0, (512 + 8192) * sizeof(float), stream);

    k_degi<<<(N_EDGES + 255) / 256, 256, 0, stream>>>(ei + N_EDGES, ideg);
    k_scan1<<<NB_SCAN, 1024, 0, stream>>>(ideg, row_start, btot, deg_isqrt, cursor);
    k_scan2<<<1, 64, 0, stream>>>(btot, boff, row_start);
    k_scan3<<<NB_SCAN, 1024, 0, stream>>>(row_start, boff);
    k_fill<<<(N_EDGES + 255) / 256, 256, 0, stream>>>(ei, row_start, cursor, csr_src);

    k_gate<<<(N_NODES + 7) / 8, 256, 0, stream>>>(x, deg_isqrt, gW1, gb1, gW2, gb2, gate, xprime);
    k_gsum<32><<<(N_NODES + 7) / 8, 256, 0, stream>>>(csr_src, row_start, deg_isqrt, xprime, xp);
    k_expert<<<(N_NODES + 31) / 32, 256, 0, stream>>>(xp, Wexp, bexp, gate, h1pre);
    k_stats<<<128, 256, 0, stream>>>(h1pre, sums1);
    k_statfin<<<1, 64, 0, stream>>>(sums1, bn1g, bn1b, scsh1);
    k_w2<<<(N_NODES + 63) / 64, 256, 0, stream>>>(h1pre, scsh1, W2, deg_isqrt, yprime);
    k_gsum<16><<<(N_NODES + 15) / 16, 256, 0, stream>>>(csr_src, row_start, deg_isqrt, yprime, xp2);
    k_stats<<<128, 256, 0, stream>>>(xp2, sums2);
    k_statfin<<<1, 64, 0, stream>>>(sums2, bn2g, bn2b, scsh2);
    k_pool<<<(N_NODES + 255) / 256, 256, 0, stream>>>(xp2, scsh2, batch, psum, pmax);
    k_cls<<<1, 256, 0, stream>>>(psum, pmax, batch, clsW, clsb, out);
}

// Round 5
// 374.512 us; speedup vs baseline: 6.7845x; 1.1642x over previous
//
#include <hip/hip_runtime.h>

#define N_NODES 50000
#define N_EDGES 800000
#define F 128
#define HDIM 64
#define NE 3
#define NGRAPH 64
#define NC 3
#define BN_EPS 1e-5f
#define NB_SCAN 49   // ceil(N_NODES / 1024)

typedef __attribute__((ext_vector_type(8))) short short8;
typedef __attribute__((ext_vector_type(4))) float f32x4;

__device__ inline unsigned short f2bf(float f) {
    unsigned int u = __float_as_uint(f);
    unsigned int r = (u + 0x7FFFu + ((u >> 16) & 1u)) >> 16;
    return (unsigned short)r;
}

// ---------------- degree count (int atomics) ----------------
__global__ void k_degi(const int* __restrict__ dst, int* __restrict__ ideg) {
    int e = blockIdx.x * 256 + threadIdx.x;
    if (e < N_EDGES) atomicAdd(&ideg[dst[e]], 1);
}

// ---------------- scan stage 1 ----------------
__global__ __launch_bounds__(1024) void k_scan1(const int* __restrict__ ideg,
        int* __restrict__ row_start, int* __restrict__ btot,
        float* __restrict__ deg_isqrt, int* __restrict__ cursor) {
    __shared__ int wsums[16];
    int tid = threadIdx.x, lane = tid & 63, wid = tid >> 6;
    int i = blockIdx.x * 1024 + tid;
    int v = (i < N_NODES) ? ideg[i] : 0;
    if (i < N_NODES) {
        deg_isqrt[i] = rsqrtf((float)v + 1.0f);
        cursor[i] = 0;
    }
    int xsc = v;
    #pragma unroll
    for (int off = 1; off < 64; off <<= 1) {
        int u = __shfl_up(xsc, off, 64);
        if (lane >= off) xsc += u;
    }
    if (lane == 63) wsums[wid] = xsc;
    __syncthreads();
    if (wid == 0) {
        int wv = (lane < 16) ? wsums[lane] : 0;
        #pragma unroll
        for (int off = 1; off < 16; off <<= 1) {
            int u = __shfl_up(wv, off, 64);
            if (lane >= off) wv += u;
        }
        if (lane < 16) wsums[lane] = wv;
    }
    __syncthreads();
    int excl = (wid > 0 ? wsums[wid - 1] : 0) + (xsc - v);
    if (i < N_NODES) row_start[i] = excl;
    if (tid == 0) btot[blockIdx.x] = wsums[15];
}

// ---------------- scan stage 2 ----------------
__global__ void k_scan2(const int* __restrict__ btot, int* __restrict__ boff,
                        int* __restrict__ row_start) {
    int lane = threadIdx.x;  // 64 threads
    int v = (lane < NB_SCAN) ? btot[lane] : 0;
    int xsc = v;
    #pragma unroll
    for (int off = 1; off < 64; off <<= 1) {
        int u = __shfl_up(xsc, off, 64);
        if (lane >= off) xsc += u;
    }
    if (lane < NB_SCAN) boff[lane] = xsc - v;
    if (lane == 63) row_start[N_NODES] = xsc;
}

// ---------------- scan stage 3 ----------------
__global__ __launch_bounds__(1024) void k_scan3(int* __restrict__ row_start,
                                                const int* __restrict__ boff) {
    int i = blockIdx.x * 1024 + threadIdx.x;
    if (i < N_NODES) row_start[i] += boff[blockIdx.x];
}

// ---------------- fill CSR ----------------
__global__ void k_fill(const int* __restrict__ ei, const int* __restrict__ row_start,
                       int* __restrict__ cursor, int* __restrict__ csr_src) {
    int e = blockIdx.x * 256 + threadIdx.x;
    if (e >= N_EDGES) return;
    int s = ei[e], d = ei[N_EDGES + e];
    int slot = atomicAdd(&cursor[d], 1);
    csr_src[row_start[d] + slot] = s;
}

// ---------------- pack W_exp into MFMA B-fragment layout (bf16) ----------------
// frag f = e*16 + t*4 + kk; lane l holds B[k][h], k = kk*32+(l>>4)*8+j, h = t*16+(l&15)
__global__ void k_cvt_w(const float* __restrict__ Wexp, unsigned short* __restrict__ wpack) {
    int t0 = blockIdx.x * 256 + threadIdx.x;
    if (t0 >= 48 * 64) return;
    int f = t0 >> 6, l = t0 & 63;
    int e = f >> 4, t = (f >> 2) & 3, kk = f & 3;
    int h = t * 16 + (l & 15);
    int kbase = kk * 32 + (l >> 4) * 8;
    short8 o;
    #pragma unroll
    for (int j = 0; j < 8; ++j)
        o[j] = (short)f2bf(Wexp[e * (F * HDIM) + (kbase + j) * HDIM + h]);
    ((short8*)wpack)[f * 64 + l] = o;
}

// ---------------- gating MLP + x' = x * isq side-output ----------------
__global__ __launch_bounds__(256) void k_gate(const float* __restrict__ x,
        const float* __restrict__ deg_isqrt,
        const float* __restrict__ W1, const float* __restrict__ b1,
        const float* __restrict__ W2, const float* __restrict__ b2,
        float* __restrict__ gate, float* __restrict__ xprime) {
    __shared__ float4 xls[8][32];
    __shared__ float hs[8][32];
    int tid = threadIdx.x;
    int grp = tid >> 5, j = tid & 31;
    int n = blockIdx.x * 8 + grp;
    int nc = (n < N_NODES) ? n : N_NODES - 1;
    float4 v = ((const float4*)x)[(size_t)nc * 32 + j];
    xls[grp][j] = v;
    float si = deg_isqrt[nc];
    if (n < N_NODES)
        ((float4*)xprime)[(size_t)n * 32 + j] =
            make_float4(v.x * si, v.y * si, v.z * si, v.w * si);
    __syncthreads();
    float acc = b1[j];
    #pragma unroll 8
    for (int k4 = 0; k4 < 32; ++k4) {
        float4 xv = xls[grp][k4];
        acc = fmaf(xv.x, W1[(k4 * 4 + 0) * 32 + j], acc);
        acc = fmaf(xv.y, W1[(k4 * 4 + 1) * 32 + j], acc);
        acc = fmaf(xv.z, W1[(k4 * 4 + 2) * 32 + j], acc);
        acc = fmaf(xv.w, W1[(k4 * 4 + 3) * 32 + j], acc);
    }
    hs[grp][j] = fmaxf(acc, 0.f);
    __syncthreads();
    if (tid < 8) {
        int nn = blockIdx.x * 8 + tid;
        if (nn < N_NODES) {
            float l0 = b2[0], l1 = b2[1], l2 = b2[2];
            #pragma unroll
            for (int k = 0; k < 32; ++k) {
                float h = hs[tid][k];
                l0 = fmaf(h, W2[k * 3 + 0], l0);
                l1 = fmaf(h, W2[k * 3 + 1], l1);
                l2 = fmaf(h, W2[k * 3 + 2], l2);
            }
            float m = fmaxf(l0, fmaxf(l1, l2));
            float e0 = __expf(l0 - m), e1 = __expf(l1 - m), e2 = __expf(l2 - m);
            float inv = 1.f / (e0 + e1 + e2);
            gate[nn * 3 + 0] = e0 * inv;
            gate[nn * 3 + 1] = e1 * inv;
            gate[nn * 3 + 2] = e2 * inv;
        }
    }
}

// ---------------- GCN prop on pre-scaled features; optional bf16 output ----------------
template<int F4, bool BF16OUT>
__global__ __launch_bounds__(256) void k_gsum(const int* __restrict__ csr_src,
        const int* __restrict__ row_start, const float* __restrict__ deg_isqrt,
        const float* __restrict__ hin, void* __restrict__ out) {
    constexpr int GPB = 256 / F4;
    int lane = threadIdx.x % F4;
    int grp  = threadIdx.x / F4;
    int n = blockIdx.x * GPB + grp;
    if (n >= N_NODES) return;
    const float4* hin4 = (const float4*)hin;
    int beg = row_start[n], end = row_start[n + 1];
    float4 sv = hin4[(size_t)n * F4 + lane];
    float ax = sv.x, ay = sv.y, az = sv.z, aw = sv.w;
    int j = beg;
    for (; j + 1 < end; j += 2) {
        int s0 = csr_src[j], s1 = csr_src[j + 1];
        float4 v0 = hin4[(size_t)s0 * F4 + lane];
        float4 v1 = hin4[(size_t)s1 * F4 + lane];
        ax += v0.x; ay += v0.y; az += v0.z; aw += v0.w;
        ax += v1.x; ay += v1.y; az += v1.z; aw += v1.w;
    }
    if (j < end) {
        int s0 = csr_src[j];
        float4 v0 = hin4[(size_t)s0 * F4 + lane];
        ax += v0.x; ay += v0.y; az += v0.z; aw += v0.w;
    }
    float s = deg_isqrt[n];
    if (BF16OUT) {
        ushort4 o;
        o.x = f2bf(ax * s); o.y = f2bf(ay * s);
        o.z = f2bf(az * s); o.w = f2bf(aw * s);
        ((ushort4*)out)[(size_t)n * F4 + lane] = o;
    } else {
        ((float4*)out)[(size_t)n * F4 + lane] = make_float4(ax * s, ay * s, az * s, aw * s);
    }
}

// ---------------- experts + gated combine via MFMA bf16 ----------------
// wave w of 4: nodes n0 = blk*64 + w*16; computes [16 nodes] x [192 expert-h]
__global__ __launch_bounds__(256) void k_expert(const unsigned short* __restrict__ xp,
        const unsigned short* __restrict__ wpack, const float* __restrict__ bexp,
        const float* __restrict__ gate, float* __restrict__ h1pre) {
    int tid = threadIdx.x;
    int w = tid >> 6, l = tid & 63;
    int n0 = blockIdx.x * 64 + w * 16;
    int lo = l & 15, hi = l >> 4;
    // A fragments: lane holds xp[n0+lo][kk*32 + hi*8 .. +7]
    int arow = n0 + lo; if (arow >= N_NODES) arow = N_NODES - 1;
    const short8* xr = (const short8*)xp + (size_t)arow * 16;
    short8 a0 = xr[hi], a1 = xr[4 + hi], a2 = xr[8 + hi], a3 = xr[12 + hi];
    const short8* wp8 = (const short8*)wpack;
    float comb[4][4];
    #pragma unroll
    for (int t = 0; t < 4; ++t)
        #pragma unroll
        for (int r = 0; r < 4; ++r) comb[t][r] = 0.f;
    int nrow[4];
    #pragma unroll
    for (int r = 0; r < 4; ++r) {
        int n = n0 + hi * 4 + r;
        nrow[r] = (n < N_NODES) ? n : -1;
    }
    #pragma unroll
    for (int e = 0; e < NE; ++e) {
        float g_[4];
        #pragma unroll
        for (int r = 0; r < 4; ++r) g_[r] = (nrow[r] >= 0) ? gate[nrow[r] * 3 + e] : 0.f;
        #pragma unroll
        for (int t = 0; t < 4; ++t) {
            int fbase = (e * 16 + t * 4) * 64 + l;
            f32x4 acc = {0.f, 0.f, 0.f, 0.f};
            acc = __builtin_amdgcn_mfma_f32_16x16x32_bf16(a0, wp8[fbase      ], acc, 0, 0, 0);
            acc = __builtin_amdgcn_mfma_f32_16x16x32_bf16(a1, wp8[fbase +  64], acc, 0, 0, 0);
            acc = __builtin_amdgcn_mfma_f32_16x16x32_bf16(a2, wp8[fbase + 128], acc, 0, 0, 0);
            acc = __builtin_amdgcn_mfma_f32_16x16x32_bf16(a3, wp8[fbase + 192], acc, 0, 0, 0);
            float be = bexp[e * HDIM + t * 16 + lo];
            #pragma unroll
            for (int r = 0; r < 4; ++r) comb[t][r] = fmaf(g_[r], acc[r] + be, comb[t][r]);
        }
    }
    #pragma unroll
    for (int t = 0; t < 4; ++t)
        #pragma unroll
        for (int r = 0; r < 4; ++r)
            if (nrow[r] >= 0) h1pre[(size_t)nrow[r] * HDIM + t * 16 + lo] = comb[t][r];
}

// ---------------- column sums / sumsq for batchnorm ----------------
__global__ __launch_bounds__(256) void k_stats(const float* __restrict__ hm, float* __restrict__ sums) {
    int tid = threadIdx.x;
    int c = tid & 63, q = tid >> 6;
    float s = 0.f, s2 = 0.f;
    for (int r = blockIdx.x * 4 + q; r < N_NODES; r += gridDim.x * 4) {
        float v = hm[(size_t)r * 64 + c];
        s += v; s2 = fmaf(v, v, s2);
    }
    __shared__ float red[2][4][64];
    red[0][q][c] = s; red[1][q][c] = s2;
    __syncthreads();
    if (q == 0) {
        s  = red[0][0][c] + red[0][1][c] + red[0][2][c] + red[0][3][c];
        s2 = red[1][0][c] + red[1][1][c] + red[1][2][c] + red[1][3][c];
        atomicAdd(&sums[c], s);
        atomicAdd(&sums[64 + c], s2);
    }
}

__global__ void k_statfin(const float* __restrict__ sums, const float* __restrict__ g,
                          const float* __restrict__ b, float* __restrict__ scsh) {
    int c = threadIdx.x;  // 64 threads
    float mu = sums[c] * (1.0f / N_NODES);
    float var = sums[64 + c] * (1.0f / N_NODES) - mu * mu;
    float rs = rsqrtf(var + BN_EPS);
    float sc = rs * g[c];
    scsh[c] = sc;
    scsh[64 + c] = b[c] - mu * sc;
}

// ---------------- bn1 + relu fused into h1 @ W2, epilogue scales by isq ----------------
__global__ __launch_bounds__(256) void k_w2(const float* __restrict__ h1pre,
        const float* __restrict__ scsh, const float* __restrict__ W2,
        const float* __restrict__ deg_isqrt, float* __restrict__ y) {
    __shared__ float4 hsd[64 * 16];  // 16 KB
    __shared__ float  wsd[64 * 64];  // 16 KB
    int tid = threadIdx.x;
    int nbase = blockIdx.x * 64;
    for (int i = tid; i < 64 * 16; i += 256) ((float4*)wsd)[i] = ((const float4*)W2)[i];
    for (int i = tid; i < 64 * 16; i += 256) {
        int r = i >> 4, c = i & 15;
        int n = nbase + r; if (n >= N_NODES) n = N_NODES - 1;
        float4 v  = ((const float4*)h1pre)[(size_t)n * 16 + c];
        float4 sc = ((const float4*)scsh)[c];
        float4 sh = ((const float4*)scsh)[16 + c];
        v.x = fmaxf(fmaf(v.x, sc.x, sh.x), 0.f);
        v.y = fmaxf(fmaf(v.y, sc.y, sh.y), 0.f);
        v.z = fmaxf(fmaf(v.z, sc.z, sh.z), 0.f);
        v.w = fmaxf(fmaf(v.w, sc.w, sh.w), 0.f);
        hsd[i] = v;
    }
    __syncthreads();
    int h = tid & 63, iq = tid >> 6;
    float acc[16];
    #pragma unroll
    for (int i = 0; i < 16; ++i) acc[i] = 0.f;
    for (int k4 = 0; k4 < 16; ++k4) {
        float w0 = wsd[(k4 * 4 + 0) * 64 + h];
        float w1 = wsd[(k4 * 4 + 1) * 64 + h];
        float w2v = wsd[(k4 * 4 + 2) * 64 + h];
        float w3 = wsd[(k4 * 4 + 3) * 64 + h];
        #pragma unroll
        for (int i = 0; i < 16; ++i) {
            float4 xv = hsd[(iq * 16 + i) * 16 + k4];
            acc[i] = fmaf(xv.x, w0, acc[i]);
            acc[i] = fmaf(xv.y, w1, acc[i]);
            acc[i] = fmaf(xv.z, w2v, acc[i]);
            acc[i] = fmaf(xv.w, w3, acc[i]);
        }
    }
    #pragma unroll
    for (int i = 0; i < 16; ++i) {
        int n = nbase + iq * 16 + i;
        if (n < N_NODES) y[(size_t)n * 64 + h] = acc[i] * deg_isqrt[n];
    }
}

// ---------------- bn2 + relu + pooling ----------------
__global__ __launch_bounds__(256) void k_pool(const float* __restrict__ xp2,
        const float* __restrict__ scsh2, const int* __restrict__ batch,
        float* __restrict__ psum, unsigned int* __restrict__ pmax) {
    int tid = threadIdx.x;
    int h = tid & 63, q = tid >> 6;
    float sc = scsh2[h], sh = scsh2[64 + h];
    int base = blockIdx.x * 256;
    int curg = -1; float ls = 0.f, lm = 0.f;
    for (int j = 0; j < 64; ++j) {
        int r = base + j * 4 + q;
        if (r >= N_NODES) break;
        int g = batch[r];
        if (g != curg) {
            if (curg >= 0) {
                atomicAdd(&psum[curg * 64 + h], ls);
                atomicMax(&pmax[curg * 64 + h], __float_as_uint(lm));
            }
            curg = g; ls = 0.f; lm = 0.f;
        }
        float v = fmaxf(fmaf(xp2[(size_t)r * 64 + h], sc, sh), 0.f);
        ls += v; lm = fmaxf(lm, v);
    }
    if (curg >= 0) {
        atomicAdd(&psum[curg * 64 + h], ls);
        atomicMax(&pmax[curg * 64 + h], __float_as_uint(lm));
    }
}

// ---------------- classifier ----------------
__global__ void k_cls(const float* __restrict__ psum, const unsigned int* __restrict__ pmax,
                      const int* __restrict__ batch, const float* __restrict__ Wc,
                      const float* __restrict__ bc, float* __restrict__ out) {
    int t = threadIdx.x;
    if (t >= NGRAPH * NC) return;
    int g = t / NC, c = t % NC;
    int lo = 0, hi = N_NODES;
    while (lo < hi) { int mid = (lo + hi) >> 1; if (batch[mid] < g) lo = mid + 1; else hi = mid; }
    int lb = lo;
    hi = N_NODES;
    while (lo < hi) { int mid = (lo + hi) >> 1; if (batch[mid] < g + 1) lo = mid + 1; else hi = mid; }
    float cnt = (float)(lo - lb);
    float invc = 1.f / fmaxf(cnt, 1.f);
    float acc = bc[c];
    #pragma unroll 8
    for (int j = 0; j < 64; ++j) {
        float s = psum[g * 64 + j];
        float mx = __uint_as_float(pmax[g * 64 + j]);
        acc = fmaf(s * invc, Wc[j * 3 + c], acc);
        acc = fmaf(mx, Wc[(64 + j) * 3 + c], acc);
        acc = fmaf(s, Wc[(128 + j) * 3 + c], acc);
    }
    out[g * NC + c] = acc;
}

extern "C" void kernel_launch(void* const* d_in, const int* in_sizes, int n_in,
                              void* d_out, int out_size, void* d_ws, size_t ws_size,
                              hipStream_t stream) {
    const float* x    = (const float*)d_in[0];
    const int*   ei   = (const int*)d_in[1];
    const int*   batch= (const int*)d_in[2];
    const float* Wexp = (const float*)d_in[3];
    const float* bexp = (const float*)d_in[4];
    const float* gW1  = (const float*)d_in[5];
    const float* gb1  = (const float*)d_in[6];
    const float* gW2  = (const float*)d_in[7];
    const float* gb2  = (const float*)d_in[8];
    const float* W2   = (const float*)d_in[9];
    // d_in[10] = b2: cancels inside bn2 (per-column constant shift)
    const float* bn1g = (const float*)d_in[11];
    const float* bn1b = (const float*)d_in[12];
    const float* bn2g = (const float*)d_in[13];
    const float* bn2b = (const float*)d_in[14];
    const float* clsW = (const float*)d_in[15];
    const float* clsb = (const float*)d_in[16];
    float* out = (float*)d_out;

    float* ws = (float*)d_ws;
    const size_t NN = N_NODES;
    // timeline-safe overlays:
    float* deg_isqrt = ws;                         // N
    int*   cursor    = (int*)(ws + NN);            // N
    float* gate      = ws + 2 * NN;                // 3N
    float* xprime    = ws + 5 * NN;                // 128N fp32 (dead after gsum32)
    float* h1pre     = ws + 5 * NN;                // 64N (overlays xprime head)
    float* yprime    = ws + 69 * NN;               // 64N (overlays xprime tail)
    unsigned short* xpb = (unsigned short*)(ws + 133 * NN);  // N*128 bf16 (dead after expert)
    float* xp2       = ws + 133 * NN;              // 64N fp32 (overlays dead xpb)
    float* stats     = ws + 197 * NN;
    float* sums1 = stats;        float* scsh1 = stats + 128;
    float* sums2 = stats + 256;  float* scsh2 = stats + 384;
    float* psum  = stats + 512;                              // G*64
    unsigned int* pmax = (unsigned int*)(stats + 512 + 4096);
    int* ideg      = (int*)(ws + 197 * NN + 16384);          // N
    int* row_start = ideg + NN;                              // N+1 (+pad)
    int* btot      = row_start + NN + 8;                     // 64
    int* boff      = btot + 64;                              // 64
    int* csr_src   = boff + 64;                              // E
    unsigned short* wpack = (unsigned short*)(csr_src + N_EDGES);  // 24576 bf16

    hipMemsetAsync(ideg, 0, NN * sizeof(int), stream);
    hipMemsetAsync(stats, 0, (512 + 8192) * sizeof(float), stream);

    k_cvt_w<<<12, 256, 0, stream>>>(Wexp, wpack);
    k_degi<<<(N_EDGES + 255) / 256, 256, 0, stream>>>(ei + N_EDGES, ideg);
    k_scan1<<<NB_SCAN, 1024, 0, stream>>>(ideg, row_start, btot, deg_isqrt, cursor);
    k_scan2<<<1, 64, 0, stream>>>(btot, boff, row_start);
    k_scan3<<<NB_SCAN, 1024, 0, stream>>>(row_start, boff);
    k_fill<<<(N_EDGES + 255) / 256, 256, 0, stream>>>(ei, row_start, cursor, csr_src);

    k_gate<<<(N_NODES + 7) / 8, 256, 0, stream>>>(x, deg_isqrt, gW1, gb1, gW2, gb2, gate, xprime);
    k_gsum<32, true><<<(N_NODES + 7) / 8, 256, 0, stream>>>(csr_src, row_start, deg_isqrt, xprime, xpb);
    k_expert<<<(N_NODES + 63) / 64, 256, 0, stream>>>(xpb, wpack, bexp, gate, h1pre);
    k_stats<<<128, 256, 0, stream>>>(h1pre, sums1);
    k_statfin<<<1, 64, 0, stream>>>(sums1, bn1g, bn1b, scsh1);
    k_w2<<<(N_NODES + 63) / 64, 256, 0, stream>>>(h1pre, scsh1, W2, deg_isqrt, yprime);
    k_gsum<16, false><<<(N_NODES + 15) / 16, 256, 0, stream>>>(csr_src, row_start, deg_isqrt, yprime, xp2);
    k_stats<<<128, 256, 0, stream>>>(xp2, sums2);
    k_statfin<<<1, 64, 0, stream>>>(sums2, bn2g, bn2b, scsh2);
    k_pool<<<(N_NODES + 255) / 256, 256, 0, stream>>>(xp2, scsh2, batch, psum, pmax);
    k_cls<<<1, 256, 0, stream>>>(psum, pmax, batch, clsW, clsb, out);
}

// Round 6
// 287.320 us; speedup vs baseline: 8.8433x; 1.3035x over previous
//
#include <hip/hip_runtime.h>

#define N_NODES 50000
#define N_EDGES 800000
#define F 128
#define HDIM 64
#define NE 3
#define NGRAPH 64
#define NC 3
#define BN_EPS 1e-5f
#define NB_SCAN 49   // ceil(N_NODES / 1024)

typedef __attribute__((ext_vector_type(8))) short short8;
typedef __attribute__((ext_vector_type(4))) float f32x4;

__device__ inline unsigned short f2bf(float f) {
    unsigned int u = __float_as_uint(f);
    unsigned int r = (u + 0x7FFFu + ((u >> 16) & 1u)) >> 16;
    return (unsigned short)r;
}
__device__ inline float bf2f(unsigned short u) {
    return __uint_as_float(((unsigned int)u) << 16);
}

// ---------------- degree count (int atomics) ----------------
__global__ void k_degi(const int* __restrict__ dst, int* __restrict__ ideg) {
    int e = blockIdx.x * 256 + threadIdx.x;
    if (e < N_EDGES) atomicAdd(&ideg[dst[e]], 1);
}

// ---------------- scan stage 1 ----------------
__global__ __launch_bounds__(1024) void k_scan1(const int* __restrict__ ideg,
        int* __restrict__ row_start, int* __restrict__ btot,
        float* __restrict__ deg_isqrt, int* __restrict__ cursor) {
    __shared__ int wsums[16];
    int tid = threadIdx.x, lane = tid & 63, wid = tid >> 6;
    int i = blockIdx.x * 1024 + tid;
    int v = (i < N_NODES) ? ideg[i] : 0;
    if (i < N_NODES) {
        deg_isqrt[i] = rsqrtf((float)v + 1.0f);
        cursor[i] = 0;
    }
    int xsc = v;
    #pragma unroll
    for (int off = 1; off < 64; off <<= 1) {
        int u = __shfl_up(xsc, off, 64);
        if (lane >= off) xsc += u;
    }
    if (lane == 63) wsums[wid] = xsc;
    __syncthreads();
    if (wid == 0) {
        int wv = (lane < 16) ? wsums[lane] : 0;
        #pragma unroll
        for (int off = 1; off < 16; off <<= 1) {
            int u = __shfl_up(wv, off, 64);
            if (lane >= off) wv += u;
        }
        if (lane < 16) wsums[lane] = wv;
    }
    __syncthreads();
    int excl = (wid > 0 ? wsums[wid - 1] : 0) + (xsc - v);
    if (i < N_NODES) row_start[i] = excl;
    if (tid == 0) btot[blockIdx.x] = wsums[15];
}

// ---------------- scan stage 2 ----------------
__global__ void k_scan2(const int* __restrict__ btot, int* __restrict__ boff,
                        int* __restrict__ row_start) {
    int lane = threadIdx.x;  // 64 threads
    int v = (lane < NB_SCAN) ? btot[lane] : 0;
    int xsc = v;
    #pragma unroll
    for (int off = 1; off < 64; off <<= 1) {
        int u = __shfl_up(xsc, off, 64);
        if (lane >= off) xsc += u;
    }
    if (lane < NB_SCAN) boff[lane] = xsc - v;
    if (lane == 63) row_start[N_NODES] = xsc;
}

// ---------------- scan stage 3 ----------------
__global__ __launch_bounds__(1024) void k_scan3(int* __restrict__ row_start,
                                                const int* __restrict__ boff) {
    int i = blockIdx.x * 1024 + threadIdx.x;
    if (i < N_NODES) row_start[i] += boff[blockIdx.x];
}

// ---------------- fill CSR ----------------
__global__ void k_fill(const int* __restrict__ ei, const int* __restrict__ row_start,
                       int* __restrict__ cursor, int* __restrict__ csr_src) {
    int e = blockIdx.x * 256 + threadIdx.x;
    if (e >= N_EDGES) return;
    int s = ei[e], d = ei[N_EDGES + e];
    int slot = atomicAdd(&cursor[d], 1);
    csr_src[row_start[d] + slot] = s;
}

// ---------------- graph segment starts (batch is sorted) ----------------
__global__ void k_gseg(const int* __restrict__ batch, int* __restrict__ gstart) {
    int g = threadIdx.x;
    if (g > NGRAPH) return;
    int lo = 0, hi = N_NODES;
    while (lo < hi) { int m = (lo + hi) >> 1; if (batch[m] < g) lo = m + 1; else hi = m; }
    gstart[g] = lo;
}

// ---------------- pack W_exp into MFMA B-fragment layout (bf16) ----------------
__global__ void k_cvt_w(const float* __restrict__ Wexp, unsigned short* __restrict__ wpack) {
    int t0 = blockIdx.x * 256 + threadIdx.x;
    if (t0 >= 48 * 64) return;
    int f = t0 >> 6, l = t0 & 63;
    int e = f >> 4, t = (f >> 2) & 3, kk = f & 3;
    int h = t * 16 + (l & 15);
    int kbase = kk * 32 + (l >> 4) * 8;
    short8 o;
    #pragma unroll
    for (int j = 0; j < 8; ++j)
        o[j] = (short)f2bf(Wexp[e * (F * HDIM) + (kbase + j) * HDIM + h]);
    ((short8*)wpack)[f * 64 + l] = o;
}

// ---------------- gating MLP + x' = x * isq (bf16 side-output) ----------------
__global__ __launch_bounds__(256) void k_gate(const float* __restrict__ x,
        const float* __restrict__ deg_isqrt,
        const float* __restrict__ W1, const float* __restrict__ b1,
        const float* __restrict__ W2, const float* __restrict__ b2,
        float* __restrict__ gate, unsigned short* __restrict__ xpb1) {
    __shared__ float4 xls[8][32];
    __shared__ float hs[8][32];
    int tid = threadIdx.x;
    int grp = tid >> 5, j = tid & 31;
    int n = blockIdx.x * 8 + grp;
    int nc = (n < N_NODES) ? n : N_NODES - 1;
    float4 v = ((const float4*)x)[(size_t)nc * 32 + j];
    xls[grp][j] = v;
    float si = deg_isqrt[nc];
    if (n < N_NODES) {
        ushort4 o;
        o.x = f2bf(v.x * si); o.y = f2bf(v.y * si);
        o.z = f2bf(v.z * si); o.w = f2bf(v.w * si);
        ((ushort4*)xpb1)[(size_t)n * 32 + j] = o;
    }
    __syncthreads();
    float acc = b1[j];
    #pragma unroll 8
    for (int k4 = 0; k4 < 32; ++k4) {
        float4 xv = xls[grp][k4];
        acc = fmaf(xv.x, W1[(k4 * 4 + 0) * 32 + j], acc);
        acc = fmaf(xv.y, W1[(k4 * 4 + 1) * 32 + j], acc);
        acc = fmaf(xv.z, W1[(k4 * 4 + 2) * 32 + j], acc);
        acc = fmaf(xv.w, W1[(k4 * 4 + 3) * 32 + j], acc);
    }
    hs[grp][j] = fmaxf(acc, 0.f);
    __syncthreads();
    if (tid < 8) {
        int nn = blockIdx.x * 8 + tid;
        if (nn < N_NODES) {
            float l0 = b2[0], l1 = b2[1], l2 = b2[2];
            #pragma unroll
            for (int k = 0; k < 32; ++k) {
                float h = hs[tid][k];
                l0 = fmaf(h, W2[k * 3 + 0], l0);
                l1 = fmaf(h, W2[k * 3 + 1], l1);
                l2 = fmaf(h, W2[k * 3 + 2], l2);
            }
            float m = fmaxf(l0, fmaxf(l1, l2));
            float e0 = __expf(l0 - m), e1 = __expf(l1 - m), e2 = __expf(l2 - m);
            float inv = 1.f / (e0 + e1 + e2);
            gate[nn * 3 + 0] = e0 * inv;
            gate[nn * 3 + 1] = e1 * inv;
            gate[nn * 3 + 2] = e2 * inv;
        }
    }
}

// ---------------- stage-1 prop, bf16 in / bf16 out (F=128: 16 lanes/node) ----------------
__global__ __launch_bounds__(256) void k_gsum_x(const int* __restrict__ csr_src,
        const int* __restrict__ row_start, const float* __restrict__ deg_isqrt,
        const unsigned short* __restrict__ hin, unsigned short* __restrict__ out) {
    int lane = threadIdx.x & 15;
    int grp  = threadIdx.x >> 4;
    int n = blockIdx.x * 16 + grp;
    if (n >= N_NODES) return;
    const short8* h8 = (const short8*)hin;
    int beg = row_start[n], end = row_start[n + 1];
    short8 sv = h8[(size_t)n * 16 + lane];
    float a[8];
    #pragma unroll
    for (int j = 0; j < 8; ++j) a[j] = bf2f((unsigned short)sv[j]);
    int e = beg;
    for (; e + 1 < end; e += 2) {
        int s0 = csr_src[e], s1 = csr_src[e + 1];
        short8 v0 = h8[(size_t)s0 * 16 + lane];
        short8 v1 = h8[(size_t)s1 * 16 + lane];
        #pragma unroll
        for (int j = 0; j < 8; ++j) a[j] += bf2f((unsigned short)v0[j]);
        #pragma unroll
        for (int j = 0; j < 8; ++j) a[j] += bf2f((unsigned short)v1[j]);
    }
    if (e < end) {
        short8 v0 = h8[(size_t)csr_src[e] * 16 + lane];
        #pragma unroll
        for (int j = 0; j < 8; ++j) a[j] += bf2f((unsigned short)v0[j]);
    }
    float s = deg_isqrt[n];
    short8 o;
    #pragma unroll
    for (int j = 0; j < 8; ++j) o[j] = (short)f2bf(a[j] * s);
    ((short8*)out)[(size_t)n * 16 + lane] = o;
}

// ---------------- stage-2 prop, bf16 in / fp32 out (H=64: 8 lanes/node) ----------------
__global__ __launch_bounds__(256) void k_gsum_y(const int* __restrict__ csr_src,
        const int* __restrict__ row_start, const float* __restrict__ deg_isqrt,
        const unsigned short* __restrict__ hin, float* __restrict__ out) {
    int lane = threadIdx.x & 7;
    int grp  = threadIdx.x >> 3;
    int n = blockIdx.x * 32 + grp;
    if (n >= N_NODES) return;
    const short8* h8 = (const short8*)hin;
    int beg = row_start[n], end = row_start[n + 1];
    short8 sv = h8[(size_t)n * 8 + lane];
    float a[8];
    #pragma unroll
    for (int j = 0; j < 8; ++j) a[j] = bf2f((unsigned short)sv[j]);
    int e = beg;
    for (; e + 1 < end; e += 2) {
        int s0 = csr_src[e], s1 = csr_src[e + 1];
        short8 v0 = h8[(size_t)s0 * 8 + lane];
        short8 v1 = h8[(size_t)s1 * 8 + lane];
        #pragma unroll
        for (int j = 0; j < 8; ++j) a[j] += bf2f((unsigned short)v0[j]);
        #pragma unroll
        for (int j = 0; j < 8; ++j) a[j] += bf2f((unsigned short)v1[j]);
    }
    if (e < end) {
        short8 v0 = h8[(size_t)csr_src[e] * 8 + lane];
        #pragma unroll
        for (int j = 0; j < 8; ++j) a[j] += bf2f((unsigned short)v0[j]);
    }
    float s = deg_isqrt[n];
    float4 o0 = make_float4(a[0] * s, a[1] * s, a[2] * s, a[3] * s);
    float4 o1 = make_float4(a[4] * s, a[5] * s, a[6] * s, a[7] * s);
    ((float4*)out)[(size_t)n * 16 + lane * 2]     = o0;
    ((float4*)out)[(size_t)n * 16 + lane * 2 + 1] = o1;
}

// ---------------- experts + gated combine via MFMA bf16 ----------------
__global__ __launch_bounds__(256) void k_expert(const unsigned short* __restrict__ xp,
        const unsigned short* __restrict__ wpack, const float* __restrict__ bexp,
        const float* __restrict__ gate, float* __restrict__ h1pre) {
    int tid = threadIdx.x;
    int w = tid >> 6, l = tid & 63;
    int n0 = blockIdx.x * 64 + w * 16;
    int lo = l & 15, hi = l >> 4;
    int arow = n0 + lo; if (arow >= N_NODES) arow = N_NODES - 1;
    const short8* xr = (const short8*)xp + (size_t)arow * 16;
    short8 a0 = xr[hi], a1 = xr[4 + hi], a2 = xr[8 + hi], a3 = xr[12 + hi];
    const short8* wp8 = (const short8*)wpack;
    float comb[4][4];
    #pragma unroll
    for (int t = 0; t < 4; ++t)
        #pragma unroll
        for (int r = 0; r < 4; ++r) comb[t][r] = 0.f;
    int nrow[4];
    #pragma unroll
    for (int r = 0; r < 4; ++r) {
        int n = n0 + hi * 4 + r;
        nrow[r] = (n < N_NODES) ? n : -1;
    }
    #pragma unroll
    for (int e = 0; e < NE; ++e) {
        float g_[4];
        #pragma unroll
        for (int r = 0; r < 4; ++r) g_[r] = (nrow[r] >= 0) ? gate[nrow[r] * 3 + e] : 0.f;
        #pragma unroll
        for (int t = 0; t < 4; ++t) {
            int fbase = (e * 16 + t * 4) * 64 + l;
            f32x4 acc = {0.f, 0.f, 0.f, 0.f};
            acc = __builtin_amdgcn_mfma_f32_16x16x32_bf16(a0, wp8[fbase      ], acc, 0, 0, 0);
            acc = __builtin_amdgcn_mfma_f32_16x16x32_bf16(a1, wp8[fbase +  64], acc, 0, 0, 0);
            acc = __builtin_amdgcn_mfma_f32_16x16x32_bf16(a2, wp8[fbase + 128], acc, 0, 0, 0);
            acc = __builtin_amdgcn_mfma_f32_16x16x32_bf16(a3, wp8[fbase + 192], acc, 0, 0, 0);
            float be = bexp[e * HDIM + t * 16 + lo];
            #pragma unroll
            for (int r = 0; r < 4; ++r) comb[t][r] = fmaf(g_[r], acc[r] + be, comb[t][r]);
        }
    }
    #pragma unroll
    for (int t = 0; t < 4; ++t)
        #pragma unroll
        for (int r = 0; r < 4; ++r)
            if (nrow[r] >= 0) h1pre[(size_t)nrow[r] * HDIM + t * 16 + lo] = comb[t][r];
}

// ---------------- column sums / sumsq for batchnorm ----------------
__global__ __launch_bounds__(256) void k_stats(const float* __restrict__ hm, float* __restrict__ sums) {
    int tid = threadIdx.x;
    int c = tid & 63, q = tid >> 6;
    float s = 0.f, s2 = 0.f;
    for (int r = blockIdx.x * 4 + q; r < N_NODES; r += gridDim.x * 4) {
        float v = hm[(size_t)r * 64 + c];
        s += v; s2 = fmaf(v, v, s2);
    }
    __shared__ float red[2][4][64];
    red[0][q][c] = s; red[1][q][c] = s2;
    __syncthreads();
    if (q == 0) {
        s  = red[0][0][c] + red[0][1][c] + red[0][2][c] + red[0][3][c];
        s2 = red[1][0][c] + red[1][1][c] + red[1][2][c] + red[1][3][c];
        atomicAdd(&sums[c], s);
        atomicAdd(&sums[64 + c], s2);
    }
}

__global__ void k_statfin(const float* __restrict__ sums, const float* __restrict__ g,
                          const float* __restrict__ b, float* __restrict__ scsh) {
    int c = threadIdx.x;  // 64 threads
    float mu = sums[c] * (1.0f / N_NODES);
    float var = sums[64 + c] * (1.0f / N_NODES) - mu * mu;
    float rs = rsqrtf(var + BN_EPS);
    float sc = rs * g[c];
    scsh[c] = sc;
    scsh[64 + c] = b[c] - mu * sc;
}

// ---------------- bn1 + relu fused into h1 @ W2, epilogue scales by isq -> bf16 ----------------
__global__ __launch_bounds__(256) void k_w2(const float* __restrict__ h1pre,
        const float* __restrict__ scsh, const float* __restrict__ W2,
        const float* __restrict__ deg_isqrt, unsigned short* __restrict__ y) {
    __shared__ float4 hsd[64 * 16];  // 16 KB
    __shared__ float  wsd[64 * 64];  // 16 KB
    int tid = threadIdx.x;
    int nbase = blockIdx.x * 64;
    for (int i = tid; i < 64 * 16; i += 256) ((float4*)wsd)[i] = ((const float4*)W2)[i];
    for (int i = tid; i < 64 * 16; i += 256) {
        int r = i >> 4, c = i & 15;
        int n = nbase + r; if (n >= N_NODES) n = N_NODES - 1;
        float4 v  = ((const float4*)h1pre)[(size_t)n * 16 + c];
        float4 sc = ((const float4*)scsh)[c];
        float4 sh = ((const float4*)scsh)[16 + c];
        v.x = fmaxf(fmaf(v.x, sc.x, sh.x), 0.f);
        v.y = fmaxf(fmaf(v.y, sc.y, sh.y), 0.f);
        v.z = fmaxf(fmaf(v.z, sc.z, sh.z), 0.f);
        v.w = fmaxf(fmaf(v.w, sc.w, sh.w), 0.f);
        hsd[i] = v;
    }
    __syncthreads();
    int h = tid & 63, iq = tid >> 6;
    float acc[16];
    #pragma unroll
    for (int i = 0; i < 16; ++i) acc[i] = 0.f;
    for (int k4 = 0; k4 < 16; ++k4) {
        float w0 = wsd[(k4 * 4 + 0) * 64 + h];
        float w1 = wsd[(k4 * 4 + 1) * 64 + h];
        float w2v = wsd[(k4 * 4 + 2) * 64 + h];
        float w3 = wsd[(k4 * 4 + 3) * 64 + h];
        #pragma unroll
        for (int i = 0; i < 16; ++i) {
            float4 xv = hsd[(iq * 16 + i) * 16 + k4];
            acc[i] = fmaf(xv.x, w0, acc[i]);
            acc[i] = fmaf(xv.y, w1, acc[i]);
            acc[i] = fmaf(xv.z, w2v, acc[i]);
            acc[i] = fmaf(xv.w, w3, acc[i]);
        }
    }
    #pragma unroll
    for (int i = 0; i < 16; ++i) {
        int n = nbase + iq * 16 + i;
        if (n < N_NODES) y[(size_t)n * 64 + h] = f2bf(acc[i] * deg_isqrt[n]);
    }
}

// ---------------- bn2 + relu + segmented pooling (4 chunks/graph, low contention) ----------------
__global__ __launch_bounds__(256) void k_pool(const float* __restrict__ xp2,
        const float* __restrict__ scsh2, const int* __restrict__ gstart,
        float* __restrict__ psum, unsigned int* __restrict__ pmax) {
    int g = blockIdx.x >> 2, ck = blockIdx.x & 3;
    int tid = threadIdx.x;
    int h = tid & 63, q = tid >> 6;
    int s0 = gstart[g], s1 = gstart[g + 1];
    int len = s1 - s0;
    int cbeg = s0 + (len * ck) / 4;
    int cend = s0 + (len * (ck + 1)) / 4;
    float sc = scsh2[h], sh = scsh2[64 + h];
    float ls = 0.f, lm = 0.f;
    for (int r = cbeg + q; r < cend; r += 4) {
        float v = fmaxf(fmaf(xp2[(size_t)r * 64 + h], sc, sh), 0.f);
        ls += v; lm = fmaxf(lm, v);
    }
    __shared__ float red[2][4][64];
    red[0][q][h] = ls; red[1][q][h] = lm;
    __syncthreads();
    if (q == 0) {
        ls = red[0][0][h] + red[0][1][h] + red[0][2][h] + red[0][3][h];
        lm = fmaxf(fmaxf(red[1][0][h], red[1][1][h]), fmaxf(red[1][2][h], red[1][3][h]));
        atomicAdd(&psum[g * 64 + h], ls);
        atomicMax(&pmax[g * 64 + h], __float_as_uint(lm));
    }
}

// ---------------- classifier ----------------
__global__ void k_cls(const float* __restrict__ psum, const unsigned int* __restrict__ pmax,
                      const int* __restrict__ gstart, const float* __restrict__ Wc,
                      const float* __restrict__ bc, float* __restrict__ out) {
    int t = threadIdx.x;
    if (t >= NGRAPH * NC) return;
    int g = t / NC, c = t % NC;
    float cnt = (float)(gstart[g + 1] - gstart[g]);
    float invc = 1.f / fmaxf(cnt, 1.f);
    float acc = bc[c];
    #pragma unroll 8
    for (int j = 0; j < 64; ++j) {
        float s = psum[g * 64 + j];
        float mx = __uint_as_float(pmax[g * 64 + j]);
        acc = fmaf(s * invc, Wc[j * 3 + c], acc);
        acc = fmaf(mx, Wc[(64 + j) * 3 + c], acc);
        acc = fmaf(s, Wc[(128 + j) * 3 + c], acc);
    }
    out[g * NC + c] = acc;
}

extern "C" void kernel_launch(void* const* d_in, const int* in_sizes, int n_in,
                              void* d_out, int out_size, void* d_ws, size_t ws_size,
                              hipStream_t stream) {
    const float* x    = (const float*)d_in[0];
    const int*   ei   = (const int*)d_in[1];
    const int*   batch= (const int*)d_in[2];
    const float* Wexp = (const float*)d_in[3];
    const float* bexp = (const float*)d_in[4];
    const float* gW1  = (const float*)d_in[5];
    const float* gb1  = (const float*)d_in[6];
    const float* gW2  = (const float*)d_in[7];
    const float* gb2  = (const float*)d_in[8];
    const float* W2   = (const float*)d_in[9];
    // d_in[10] = b2: cancels inside bn2 (per-column constant shift)
    const float* bn1g = (const float*)d_in[11];
    const float* bn1b = (const float*)d_in[12];
    const float* bn2g = (const float*)d_in[13];
    const float* bn2b = (const float*)d_in[14];
    const float* clsW = (const float*)d_in[15];
    const float* clsb = (const float*)d_in[16];
    float* out = (float*)d_out;

    float* ws = (float*)d_ws;
    const size_t NN = N_NODES;
    // timeline-safe overlays:
    float* deg_isqrt = ws;                                   // N
    int*   cursor    = (int*)(ws + NN);                      // N
    float* gate      = ws + 2 * NN;                          // 3N
    unsigned short* xpb1 = (unsigned short*)(ws + 5 * NN);   // N*128 bf16 = 64N f (dead after gsum_x)
    unsigned short* ypb  = (unsigned short*)(ws + 5 * NN);   // N*64 bf16 (overlays dead xpb1)
    float* h1pre     = ws + 69 * NN;                         // 64N fp32
    unsigned short* xpb = (unsigned short*)(ws + 133 * NN);  // N*128 bf16 (dead after expert)
    float* xp2       = ws + 133 * NN;                        // 64N fp32 (overlays dead xpb)
    float* stats     = ws + 197 * NN;
    float* sums1 = stats;        float* scsh1 = stats + 128;
    float* sums2 = stats + 256;  float* scsh2 = stats + 384;
    float* psum  = stats + 512;                              // G*64
    unsigned int* pmax = (unsigned int*)(stats + 512 + 4096);
    int* gstart   = (int*)(stats + 512 + 8192);              // G+1
    int* ideg      = (int*)(ws + 197 * NN + 16384);          // N
    int* row_start = ideg + NN;                              // N+1 (+pad)
    int* btot      = row_start + NN + 8;                     // 64
    int* boff      = btot + 64;                              // 64
    int* csr_src   = boff + 64;                              // E
    unsigned short* wpack = (unsigned short*)(csr_src + N_EDGES);  // 24576 bf16

    hipMemsetAsync(ideg, 0, NN * sizeof(int), stream);
    hipMemsetAsync(stats, 0, (512 + 8192) * sizeof(float), stream);

    k_cvt_w<<<12, 256, 0, stream>>>(Wexp, wpack);
    k_degi<<<(N_EDGES + 255) / 256, 256, 0, stream>>>(ei + N_EDGES, ideg);
    k_scan1<<<NB_SCAN, 1024, 0, stream>>>(ideg, row_start, btot, deg_isqrt, cursor);
    k_scan2<<<1, 64, 0, stream>>>(btot, boff, row_start);
    k_scan3<<<NB_SCAN, 1024, 0, stream>>>(row_start, boff);
    k_fill<<<(N_EDGES + 255) / 256, 256, 0, stream>>>(ei, row_start, cursor, csr_src);
    k_gseg<<<1, 128, 0, stream>>>(batch, gstart);

    k_gate<<<(N_NODES + 7) / 8, 256, 0, stream>>>(x, deg_isqrt, gW1, gb1, gW2, gb2, gate, xpb1);
    k_gsum_x<<<(N_NODES + 15) / 16, 256, 0, stream>>>(csr_src, row_start, deg_isqrt, xpb1, xpb);
    k_expert<<<(N_NODES + 63) / 64, 256, 0, stream>>>(xpb, wpack, bexp, gate, h1pre);
    k_stats<<<384, 256, 0, stream>>>(h1pre, sums1);
    k_statfin<<<1, 64, 0, stream>>>(sums1, bn1g, bn1b, scsh1);
    k_w2<<<(N_NODES + 63) / 64, 256, 0, stream>>>(h1pre, scsh1, W2, deg_isqrt, ypb);
    k_gsum_y<<<(N_NODES + 31) / 32, 256, 0, stream>>>(csr_src, row_start, deg_isqrt, ypb, xp2);
    k_stats<<<384, 256, 0, stream>>>(xp2, sums2);
    k_statfin<<<1, 64, 0, stream>>>(sums2, bn2g, bn2b, scsh2);
    k_pool<<<NGRAPH * 4, 256, 0, stream>>>(xp2, scsh2, gstart, psum, pmax);
    k_cls<<<1, 256, 0, stream>>>(psum, pmax, gstart, clsW, clsb, out);
}

// Round 7
// 232.056 us; speedup vs baseline: 10.9494x; 1.2382x over previous
//
#include <hip/hip_runtime.h>

#define N_NODES 50000
#define N_EDGES 800000
#define F 128
#define HDIM 64
#define NE 3
#define NGRAPH 64
#define NC 3
#define BN_EPS 1e-5f
#define NBLK_A 200      // histogram/place blocks, 4000 edges each
#define NBUCK 196       // ceil(N_NODES/256) buckets of 256 nodes

typedef __attribute__((ext_vector_type(8))) short short8;
typedef __attribute__((ext_vector_type(4))) float f32x4;

__device__ inline unsigned short f2bf(float f) {
    unsigned int u = __float_as_uint(f);
    unsigned int r = (u + 0x7FFFu + ((u >> 16) & 1u)) >> 16;
    return (unsigned short)r;
}
__device__ inline float bf2f(unsigned short u) {
    return __uint_as_float(((unsigned int)u) << 16);
}

// ---------------- CSR build, pass A: per-block bucket histogram ----------------
__global__ __launch_bounds__(256) void k_bhist(const int* __restrict__ dst, int* __restrict__ bh) {
    __shared__ int hist[256];
    int tid = threadIdx.x;
    hist[tid] = 0;
    __syncthreads();
    int base = blockIdx.x * 4000;
    for (int i = tid; i < 4000; i += 256)
        atomicAdd(&hist[dst[base + i] >> 8], 1);
    __syncthreads();
    bh[blockIdx.x * 256 + tid] = hist[tid];
}

// ---------------- CSR build, pass B: scan (blocks per bucket, then bucket bases) ----------------
__global__ __launch_bounds__(256) void k_bscan(int* __restrict__ bh, int* __restrict__ bucketbase,
                                               int* __restrict__ row_start) {
    int b = threadIdx.x;
    int sum = 0;
    for (int k = 0; k < NBLK_A; ++k) {
        int v = bh[k * 256 + b];
        bh[k * 256 + b] = sum;   // exclusive over blocks
        sum += v;
    }
    int lane = b & 63, wid = b >> 6;
    __shared__ int wsums[4];
    int xsc = sum;
    #pragma unroll
    for (int off = 1; off < 64; off <<= 1) {
        int u = __shfl_up(xsc, off, 64);
        if (lane >= off) xsc += u;
    }
    if (lane == 63) wsums[wid] = xsc;
    __syncthreads();
    int woff = 0;
    for (int wq = 0; wq < wid; ++wq) woff += wsums[wq];
    int excl = woff + xsc - sum;
    bucketbase[b] = excl;
    if (b == 255) {
        bucketbase[256] = excl + sum;
        row_start[N_NODES] = excl + sum;   // == N_EDGES
    }
}

// ---------------- CSR build, pass C: scatter pairs grouped by bucket ----------------
__global__ __launch_bounds__(256) void k_bplace(const int* __restrict__ ei, const int* __restrict__ bh,
        const int* __restrict__ bucketbase, int2* __restrict__ pairs) {
    __shared__ int cur[256];
    int tid = threadIdx.x;
    cur[tid] = bucketbase[tid] + bh[blockIdx.x * 256 + tid];
    __syncthreads();
    int base = blockIdx.x * 4000;
    for (int i = tid; i < 4000; i += 256) {
        int e = base + i;
        int s = ei[e], d = ei[N_EDGES + e];
        int slot = atomicAdd(&cur[d >> 8], 1);
        pairs[slot] = make_int2(s, d);
    }
}

// ---------------- CSR build, pass D: per-bucket degrees, row_start, final placement ----------------
__global__ __launch_bounds__(256) void k_bfinal(const int2* __restrict__ pairs,
        const int* __restrict__ bucketbase, int* __restrict__ row_start,
        float* __restrict__ deg_isqrt, int* __restrict__ csr_src) {
    __shared__ int deg[256];
    __shared__ int cur[256];
    __shared__ int wsums[4];
    int b = blockIdx.x, t = threadIdx.x;
    int beg = bucketbase[b], end = bucketbase[b + 1];
    deg[t] = 0;
    __syncthreads();
    for (int i = beg + t; i < end; i += 256)
        atomicAdd(&deg[pairs[i].y & 255], 1);
    __syncthreads();
    int d = deg[t];
    int lane = t & 63, wid = t >> 6;
    int xsc = d;
    #pragma unroll
    for (int off = 1; off < 64; off <<= 1) {
        int u = __shfl_up(xsc, off, 64);
        if (lane >= off) xsc += u;
    }
    if (lane == 63) wsums[wid] = xsc;
    __syncthreads();
    int woff = 0;
    for (int wq = 0; wq < wid; ++wq) woff += wsums[wq];
    int rs = beg + woff + xsc - d;     // exclusive scan -> global row start
    int node = b * 256 + t;
    if (node < N_NODES) {
        row_start[node] = rs;
        deg_isqrt[node] = rsqrtf((float)d + 1.0f);
    }
    cur[t] = rs;
    __syncthreads();
    for (int i = beg + t; i < end; i += 256) {
        int2 p = pairs[i];
        int slot = atomicAdd(&cur[p.y & 255], 1);
        csr_src[slot] = p.x;
    }
}

// ---------------- graph segment starts (batch is sorted) ----------------
__global__ void k_gseg(const int* __restrict__ batch, int* __restrict__ gstart) {
    int g = threadIdx.x;
    if (g > NGRAPH) return;
    int lo = 0, hi = N_NODES;
    while (lo < hi) { int m = (lo + hi) >> 1; if (batch[m] < g) lo = m + 1; else hi = m; }
    gstart[g] = lo;
}

// ---------------- pack W_exp into MFMA B-fragment layout (bf16) ----------------
__global__ void k_cvt_w(const float* __restrict__ Wexp, unsigned short* __restrict__ wpack) {
    int t0 = blockIdx.x * 256 + threadIdx.x;
    if (t0 >= 48 * 64) return;
    int f = t0 >> 6, l = t0 & 63;
    int e = f >> 4, t = (f >> 2) & 3, kk = f & 3;
    int h = t * 16 + (l & 15);
    int kbase = kk * 32 + (l >> 4) * 8;
    short8 o;
    #pragma unroll
    for (int j = 0; j < 8; ++j)
        o[j] = (short)f2bf(Wexp[e * (F * HDIM) + (kbase + j) * HDIM + h]);
    ((short8*)wpack)[f * 64 + l] = o;
}

// ---------------- gating MLP + x' = x * isq (bf16 side-output) ----------------
__global__ __launch_bounds__(256) void k_gate(const float* __restrict__ x,
        const float* __restrict__ deg_isqrt,
        const float* __restrict__ W1, const float* __restrict__ b1,
        const float* __restrict__ W2, const float* __restrict__ b2,
        float* __restrict__ gate, unsigned short* __restrict__ xpb1) {
    __shared__ float4 xls[8][32];
    __shared__ float hs[8][32];
    int tid = threadIdx.x;
    int grp = tid >> 5, j = tid & 31;
    int n = blockIdx.x * 8 + grp;
    int nc = (n < N_NODES) ? n : N_NODES - 1;
    float4 v = ((const float4*)x)[(size_t)nc * 32 + j];
    xls[grp][j] = v;
    float si = deg_isqrt[nc];
    if (n < N_NODES) {
        ushort4 o;
        o.x = f2bf(v.x * si); o.y = f2bf(v.y * si);
        o.z = f2bf(v.z * si); o.w = f2bf(v.w * si);
        ((ushort4*)xpb1)[(size_t)n * 32 + j] = o;
    }
    __syncthreads();
    float acc = b1[j];
    #pragma unroll 8
    for (int k4 = 0; k4 < 32; ++k4) {
        float4 xv = xls[grp][k4];
        acc = fmaf(xv.x, W1[(k4 * 4 + 0) * 32 + j], acc);
        acc = fmaf(xv.y, W1[(k4 * 4 + 1) * 32 + j], acc);
        acc = fmaf(xv.z, W1[(k4 * 4 + 2) * 32 + j], acc);
        acc = fmaf(xv.w, W1[(k4 * 4 + 3) * 32 + j], acc);
    }
    hs[grp][j] = fmaxf(acc, 0.f);
    __syncthreads();
    if (tid < 8) {
        int nn = blockIdx.x * 8 + tid;
        if (nn < N_NODES) {
            float l0 = b2[0], l1 = b2[1], l2 = b2[2];
            #pragma unroll
            for (int k = 0; k < 32; ++k) {
                float h = hs[tid][k];
                l0 = fmaf(h, W2[k * 3 + 0], l0);
                l1 = fmaf(h, W2[k * 3 + 1], l1);
                l2 = fmaf(h, W2[k * 3 + 2], l2);
            }
            float m = fmaxf(l0, fmaxf(l1, l2));
            float e0 = __expf(l0 - m), e1 = __expf(l1 - m), e2 = __expf(l2 - m);
            float inv = 1.f / (e0 + e1 + e2);
            gate[nn * 3 + 0] = e0 * inv;
            gate[nn * 3 + 1] = e1 * inv;
            gate[nn * 3 + 2] = e2 * inv;
        }
    }
}

// ---------------- stage-1 prop, bf16 in / bf16 out (F=128: 16 lanes/node) ----------------
__global__ __launch_bounds__(256) void k_gsum_x(const int* __restrict__ csr_src,
        const int* __restrict__ row_start, const float* __restrict__ deg_isqrt,
        const unsigned short* __restrict__ hin, unsigned short* __restrict__ out) {
    int lane = threadIdx.x & 15;
    int grp  = threadIdx.x >> 4;
    int n = blockIdx.x * 16 + grp;
    if (n >= N_NODES) return;
    const short8* h8 = (const short8*)hin;
    int beg = row_start[n], end = row_start[n + 1];
    short8 sv = h8[(size_t)n * 16 + lane];
    float a[8];
    #pragma unroll
    for (int j = 0; j < 8; ++j) a[j] = bf2f((unsigned short)sv[j]);
    int e = beg;
    for (; e + 1 < end; e += 2) {
        int s0 = csr_src[e], s1 = csr_src[e + 1];
        short8 v0 = h8[(size_t)s0 * 16 + lane];
        short8 v1 = h8[(size_t)s1 * 16 + lane];
        #pragma unroll
        for (int j = 0; j < 8; ++j) a[j] += bf2f((unsigned short)v0[j]);
        #pragma unroll
        for (int j = 0; j < 8; ++j) a[j] += bf2f((unsigned short)v1[j]);
    }
    if (e < end) {
        short8 v0 = h8[(size_t)csr_src[e] * 16 + lane];
        #pragma unroll
        for (int j = 0; j < 8; ++j) a[j] += bf2f((unsigned short)v0[j]);
    }
    float s = deg_isqrt[n];
    short8 o;
    #pragma unroll
    for (int j = 0; j < 8; ++j) o[j] = (short)f2bf(a[j] * s);
    ((short8*)out)[(size_t)n * 16 + lane] = o;
}

// ---------------- stage-2 prop, bf16 in / fp32 out (H=64: 8 lanes/node) ----------------
__global__ __launch_bounds__(256) void k_gsum_y(const int* __restrict__ csr_src,
        const int* __restrict__ row_start, const float* __restrict__ deg_isqrt,
        const unsigned short* __restrict__ hin, float* __restrict__ out) {
    int lane = threadIdx.x & 7;
    int grp  = threadIdx.x >> 3;
    int n = blockIdx.x * 32 + grp;
    if (n >= N_NODES) return;
    const short8* h8 = (const short8*)hin;
    int beg = row_start[n], end = row_start[n + 1];
    short8 sv = h8[(size_t)n * 8 + lane];
    float a[8];
    #pragma unroll
    for (int j = 0; j < 8; ++j) a[j] = bf2f((unsigned short)sv[j]);
    int e = beg;
    for (; e + 1 < end; e += 2) {
        int s0 = csr_src[e], s1 = csr_src[e + 1];
        short8 v0 = h8[(size_t)s0 * 8 + lane];
        short8 v1 = h8[(size_t)s1 * 8 + lane];
        #pragma unroll
        for (int j = 0; j < 8; ++j) a[j] += bf2f((unsigned short)v0[j]);
        #pragma unroll
        for (int j = 0; j < 8; ++j) a[j] += bf2f((unsigned short)v1[j]);
    }
    if (e < end) {
        short8 v0 = h8[(size_t)csr_src[e] * 8 + lane];
        #pragma unroll
        for (int j = 0; j < 8; ++j) a[j] += bf2f((unsigned short)v0[j]);
    }
    float s = deg_isqrt[n];
    float4 o0 = make_float4(a[0] * s, a[1] * s, a[2] * s, a[3] * s);
    float4 o1 = make_float4(a[4] * s, a[5] * s, a[6] * s, a[7] * s);
    ((float4*)out)[(size_t)n * 16 + lane * 2]     = o0;
    ((float4*)out)[(size_t)n * 16 + lane * 2 + 1] = o1;
}

// ---------------- experts + gated combine via MFMA bf16 ----------------
__global__ __launch_bounds__(256) void k_expert(const unsigned short* __restrict__ xp,
        const unsigned short* __restrict__ wpack, const float* __restrict__ bexp,
        const float* __restrict__ gate, float* __restrict__ h1pre) {
    int tid = threadIdx.x;
    int w = tid >> 6, l = tid & 63;
    int n0 = blockIdx.x * 64 + w * 16;
    int lo = l & 15, hi = l >> 4;
    int arow = n0 + lo; if (arow >= N_NODES) arow = N_NODES - 1;
    const short8* xr = (const short8*)xp + (size_t)arow * 16;
    short8 a0 = xr[hi], a1 = xr[4 + hi], a2 = xr[8 + hi], a3 = xr[12 + hi];
    const short8* wp8 = (const short8*)wpack;
    float comb[4][4];
    #pragma unroll
    for (int t = 0; t < 4; ++t)
        #pragma unroll
        for (int r = 0; r < 4; ++r) comb[t][r] = 0.f;
    int nrow[4];
    #pragma unroll
    for (int r = 0; r < 4; ++r) {
        int n = n0 + hi * 4 + r;
        nrow[r] = (n < N_NODES) ? n : -1;
    }
    #pragma unroll
    for (int e = 0; e < NE; ++e) {
        float g_[4];
        #pragma unroll
        for (int r = 0; r < 4; ++r) g_[r] = (nrow[r] >= 0) ? gate[nrow[r] * 3 + e] : 0.f;
        #pragma unroll
        for (int t = 0; t < 4; ++t) {
            int fbase = (e * 16 + t * 4) * 64 + l;
            f32x4 acc = {0.f, 0.f, 0.f, 0.f};
            acc = __builtin_amdgcn_mfma_f32_16x16x32_bf16(a0, wp8[fbase      ], acc, 0, 0, 0);
            acc = __builtin_amdgcn_mfma_f32_16x16x32_bf16(a1, wp8[fbase +  64], acc, 0, 0, 0);
            acc = __builtin_amdgcn_mfma_f32_16x16x32_bf16(a2, wp8[fbase + 128], acc, 0, 0, 0);
            acc = __builtin_amdgcn_mfma_f32_16x16x32_bf16(a3, wp8[fbase + 192], acc, 0, 0, 0);
            float be = bexp[e * HDIM + t * 16 + lo];
            #pragma unroll
            for (int r = 0; r < 4; ++r) comb[t][r] = fmaf(g_[r], acc[r] + be, comb[t][r]);
        }
    }
    #pragma unroll
    for (int t = 0; t < 4; ++t)
        #pragma unroll
        for (int r = 0; r < 4; ++r)
            if (nrow[r] >= 0) h1pre[(size_t)nrow[r] * HDIM + t * 16 + lo] = comb[t][r];
}

// ---------------- column sums / sumsq for batchnorm ----------------
__global__ __launch_bounds__(256) void k_stats(const float* __restrict__ hm, float* __restrict__ sums) {
    int tid = threadIdx.x;
    int c = tid & 63, q = tid >> 6;
    float s = 0.f, s2 = 0.f;
    for (int r = blockIdx.x * 4 + q; r < N_NODES; r += gridDim.x * 4) {
        float v = hm[(size_t)r * 64 + c];
        s += v; s2 = fmaf(v, v, s2);
    }
    __shared__ float red[2][4][64];
    red[0][q][c] = s; red[1][q][c] = s2;
    __syncthreads();
    if (q == 0) {
        s  = red[0][0][c] + red[0][1][c] + red[0][2][c] + red[0][3][c];
        s2 = red[1][0][c] + red[1][1][c] + red[1][2][c] + red[1][3][c];
        atomicAdd(&sums[c], s);
        atomicAdd(&sums[64 + c], s2);
    }
}

__global__ void k_statfin(const float* __restrict__ sums, const float* __restrict__ g,
                          const float* __restrict__ b, float* __restrict__ scsh) {
    int c = threadIdx.x;  // 64 threads
    float mu = sums[c] * (1.0f / N_NODES);
    float var = sums[64 + c] * (1.0f / N_NODES) - mu * mu;
    float rs = rsqrtf(var + BN_EPS);
    float sc = rs * g[c];
    scsh[c] = sc;
    scsh[64 + c] = b[c] - mu * sc;
}

// ---------------- bn1 + relu fused into h1 @ W2, epilogue scales by isq -> bf16 ----------------
__global__ __launch_bounds__(256) void k_w2(const float* __restrict__ h1pre,
        const float* __restrict__ scsh, const float* __restrict__ W2,
        const float* __restrict__ deg_isqrt, unsigned short* __restrict__ y) {
    __shared__ float4 hsd[64 * 16];  // 16 KB
    __shared__ float  wsd[64 * 64];  // 16 KB
    int tid = threadIdx.x;
    int nbase = blockIdx.x * 64;
    for (int i = tid; i < 64 * 16; i += 256) ((float4*)wsd)[i] = ((const float4*)W2)[i];
    for (int i = tid; i < 64 * 16; i += 256) {
        int r = i >> 4, c = i & 15;
        int n = nbase + r; if (n >= N_NODES) n = N_NODES - 1;
        float4 v  = ((const float4*)h1pre)[(size_t)n * 16 + c];
        float4 sc = ((const float4*)scsh)[c];
        float4 sh = ((const float4*)scsh)[16 + c];
        v.x = fmaxf(fmaf(v.x, sc.x, sh.x), 0.f);
        v.y = fmaxf(fmaf(v.y, sc.y, sh.y), 0.f);
        v.z = fmaxf(fmaf(v.z, sc.z, sh.z), 0.f);
        v.w = fmaxf(fmaf(v.w, sc.w, sh.w), 0.f);
        hsd[i] = v;
    }
    __syncthreads();
    int h = tid & 63, iq = tid >> 6;
    float acc[16];
    #pragma unroll
    for (int i = 0; i < 16; ++i) acc[i] = 0.f;
    for (int k4 = 0; k4 < 16; ++k4) {
        float w0 = wsd[(k4 * 4 + 0) * 64 + h];
        float w1 = wsd[(k4 * 4 + 1) * 64 + h];
        float w2v = wsd[(k4 * 4 + 2) * 64 + h];
        float w3 = wsd[(k4 * 4 + 3) * 64 + h];
        #pragma unroll
        for (int i = 0; i < 16; ++i) {
            float4 xv = hsd[(iq * 16 + i) * 16 + k4];
            acc[i] = fmaf(xv.x, w0, acc[i]);
            acc[i] = fmaf(xv.y, w1, acc[i]);
            acc[i] = fmaf(xv.z, w2v, acc[i]);
            acc[i] = fmaf(xv.w, w3, acc[i]);
        }
    }
    #pragma unroll
    for (int i = 0; i < 16; ++i) {
        int n = nbase + iq * 16 + i;
        if (n < N_NODES) y[(size_t)n * 64 + h] = f2bf(acc[i] * deg_isqrt[n]);
    }
}

// ---------------- bn2 + relu + segmented pooling ----------------
__global__ __launch_bounds__(256) void k_pool(const float* __restrict__ xp2,
        const float* __restrict__ scsh2, const int* __restrict__ gstart,
        float* __restrict__ psum, unsigned int* __restrict__ pmax) {
    int g = blockIdx.x >> 2, ck = blockIdx.x & 3;
    int tid = threadIdx.x;
    int h = tid & 63, q = tid >> 6;
    int s0 = gstart[g], s1 = gstart[g + 1];
    int len = s1 - s0;
    int cbeg = s0 + (len * ck) / 4;
    int cend = s0 + (len * (ck + 1)) / 4;
    float sc = scsh2[h], sh = scsh2[64 + h];
    float ls = 0.f, lm = 0.f;
    for (int r = cbeg + q; r < cend; r += 4) {
        float v = fmaxf(fmaf(xp2[(size_t)r * 64 + h], sc, sh), 0.f);
        ls += v; lm = fmaxf(lm, v);
    }
    __shared__ float red[2][4][64];
    red[0][q][h] = ls; red[1][q][h] = lm;
    __syncthreads();
    if (q == 0) {
        ls = red[0][0][h] + red[0][1][h] + red[0][2][h] + red[0][3][h];
        lm = fmaxf(fmaxf(red[1][0][h], red[1][1][h]), fmaxf(red[1][2][h], red[1][3][h]));
        atomicAdd(&psum[g * 64 + h], ls);
        atomicMax(&pmax[g * 64 + h], __float_as_uint(lm));
    }
}

// ---------------- classifier ----------------
__global__ void k_cls(const float* __restrict__ psum, const unsigned int* __restrict__ pmax,
                      const int* __restrict__ gstart, const float* __restrict__ Wc,
                      const float* __restrict__ bc, float* __restrict__ out) {
    int t = threadIdx.x;
    if (t >= NGRAPH * NC) return;
    int g = t / NC, c = t % NC;
    float cnt = (float)(gstart[g + 1] - gstart[g]);
    float invc = 1.f / fmaxf(cnt, 1.f);
    float acc = bc[c];
    #pragma unroll 8
    for (int j = 0; j < 64; ++j) {
        float s = psum[g * 64 + j];
        float mx = __uint_as_float(pmax[g * 64 + j]);
        acc = fmaf(s * invc, Wc[j * 3 + c], acc);
        acc = fmaf(mx, Wc[(64 + j) * 3 + c], acc);
        acc = fmaf(s, Wc[(128 + j) * 3 + c], acc);
    }
    out[g * NC + c] = acc;
}

extern "C" void kernel_launch(void* const* d_in, const int* in_sizes, int n_in,
                              void* d_out, int out_size, void* d_ws, size_t ws_size,
                              hipStream_t stream) {
    const float* x    = (const float*)d_in[0];
    const int*   ei   = (const int*)d_in[1];
    const int*   batch= (const int*)d_in[2];
    const float* Wexp = (const float*)d_in[3];
    const float* bexp = (const float*)d_in[4];
    const float* gW1  = (const float*)d_in[5];
    const float* gb1  = (const float*)d_in[6];
    const float* gW2  = (const float*)d_in[7];
    const float* gb2  = (const float*)d_in[8];
    const float* W2   = (const float*)d_in[9];
    // d_in[10] = b2: cancels inside bn2 (per-column constant shift)
    const float* bn1g = (const float*)d_in[11];
    const float* bn1b = (const float*)d_in[12];
    const float* bn2g = (const float*)d_in[13];
    const float* bn2b = (const float*)d_in[14];
    const float* clsW = (const float*)d_in[15];
    const float* clsb = (const float*)d_in[16];
    float* out = (float*)d_out;

    float* ws = (float*)d_ws;
    const size_t NN = N_NODES;
    // timeline-safe overlays:
    float* deg_isqrt = ws;                                   // N
    float* gate      = ws + 2 * NN;                          // 3N
    unsigned short* xpb1 = (unsigned short*)(ws + 5 * NN);   // N*128 bf16 (dead after gsum_x)
    unsigned short* ypb  = (unsigned short*)(ws + 5 * NN);   // N*64 bf16 (overlays dead xpb1)
    float* h1pre     = ws + 69 * NN;                         // 64N fp32
    unsigned short* xpb = (unsigned short*)(ws + 133 * NN);  // N*128 bf16 (dead after expert)
    float* xp2       = ws + 133 * NN;                        // 64N fp32 (overlays dead xpb)
    float* stats     = ws + 197 * NN;
    float* sums1 = stats;        float* scsh1 = stats + 128;
    float* sums2 = stats + 256;  float* scsh2 = stats + 384;
    float* psum  = stats + 512;                              // G*64
    unsigned int* pmax = (unsigned int*)(stats + 512 + 4096);
    int* gstart   = (int*)(stats + 512 + 8192);              // G+1
    int* row_start  = (int*)(ws + 197 * NN + 16384);         // N+1 (+pad)
    int* bh         = row_start + NN + 8;                    // NBLK_A*256
    int* bucketbase = bh + NBLK_A * 256;                     // 257 (+pad)
    int* csr_src    = bucketbase + 264;                      // E
    int2* pairs     = (int2*)(csr_src + N_EDGES);            // E int2
    unsigned short* wpack = (unsigned short*)(pairs + N_EDGES);  // 24576 bf16

    hipMemsetAsync(stats, 0, (512 + 8192) * sizeof(float), stream);

    k_cvt_w<<<12, 256, 0, stream>>>(Wexp, wpack);
    k_bhist<<<NBLK_A, 256, 0, stream>>>(ei + N_EDGES, bh);
    k_bscan<<<1, 256, 0, stream>>>(bh, bucketbase, row_start);
    k_bplace<<<NBLK_A, 256, 0, stream>>>(ei, bh, bucketbase, pairs);
    k_bfinal<<<NBUCK, 256, 0, stream>>>(pairs, bucketbase, row_start, deg_isqrt, csr_src);
    k_gseg<<<1, 128, 0, stream>>>(batch, gstart);

    k_gate<<<(N_NODES + 7) / 8, 256, 0, stream>>>(x, deg_isqrt, gW1, gb1, gW2, gb2, gate, xpb1);
    k_gsum_x<<<(N_NODES + 15) / 16, 256, 0, stream>>>(csr_src, row_start, deg_isqrt, xpb1, xpb);
    k_expert<<<(N_NODES + 63) / 64, 256, 0, stream>>>(xpb, wpack, bexp, gate, h1pre);
    k_stats<<<384, 256, 0, stream>>>(h1pre, sums1);
    k_statfin<<<1, 64, 0, stream>>>(sums1, bn1g, bn1b, scsh1);
    k_w2<<<(N_NODES + 63) / 64, 256, 0, stream>>>(h1pre, scsh1, W2, deg_isqrt, ypb);
    k_gsum_y<<<(N_NODES + 31) / 32, 256, 0, stream>>>(csr_src, row_start, deg_isqrt, ypb, xp2);
    k_stats<<<384, 256, 0, stream>>>(xp2, sums2);
    k_statfin<<<1, 64, 0, stream>>>(sums2, bn2g, bn2b, scsh2);
    k_pool<<<NGRAPH * 4, 256, 0, stream>>>(xp2, scsh2, gstart, psum, pmax);
    k_cls<<<1, 256, 0, stream>>>(psum, pmax, gstart, clsW, clsb, out);
}